// Round 8
// baseline (4197.673 us; speedup 1.0000x reference)
//
#include <hip/hip_runtime.h>
#include <hip/hip_bf16.h>
#include <stdint.h>

typedef __bf16 bf16_t;
typedef __bf16 bf16x8 __attribute__((ext_vector_type(8)));
typedef __bf16 bf16x4 __attribute__((ext_vector_type(4)));
typedef float  f32x16 __attribute__((ext_vector_type(16)));

#define SEQ   512
#define BATCH 32
#define HID   1024
#define FFD   4096
#define NROW  (SEQ*BATCH)          /* 16384 rows */
#define NTOT  ((long)NROW*HID)     /* 16,777,216 */
#define QKVS  3072

typedef __attribute__((address_space(3))) uint32_t lds_u32;
typedef __attribute__((address_space(1))) const uint32_t glb_u32;

__device__ __forceinline__ void gload_lds16(const void* g, void* l) {
  glb_u32* gp = reinterpret_cast<glb_u32*>(reinterpret_cast<uintptr_t>(g));
  lds_u32* lp = reinterpret_cast<lds_u32*>(reinterpret_cast<uintptr_t>(l));
  __builtin_amdgcn_global_load_lds(gp, lp, 16, 0, 0);
}

// ------------- embedding: hb = bf16(emb[x]*32 + pos[s]); init stId ---------
__global__ __launch_bounds__(256) void embed_k(const int* __restrict__ x,
    const float* __restrict__ emb, const float* __restrict__ pos,
    bf16_t* __restrict__ hb, float* __restrict__ stId)
{
  if (blockIdx.x == 0 && threadIdx.x == 0) { stId[0] = 0.f; stId[1] = 1.f; }
  const long row = blockIdx.x;           // row = s*32 + b
  const int  s   = (int)(row >> 5);
  const long idx = x[row];
  const int  t   = threadIdx.x;
  float4 e  = ((const float4*)(emb + idx*HID))[t];
  float4 pv = ((const float4*)(pos + (long)s*HID))[t];
  bf16x4 ob = {(bf16_t)(e.x*32.f+pv.x), (bf16_t)(e.y*32.f+pv.y),
               (bf16_t)(e.z*32.f+pv.z), (bf16_t)(e.w*32.f+pv.w)};
  *(bf16x4*)(hb + row*HID + (long)t*4) = ob;
}

// ---- LDS-free weight convert+transpose (512 threads/block) ----------------
// wT[n][k] = bf16(W[k][n]); block tile: 512 n-cols x 64 k.
// Reads coalesced across threads (consecutive n); writes bf16x8 per thread.
__device__ __forceinline__ void wcvtNL_body(const float* __restrict__ W,
    bf16_t* __restrict__ wT, int K, int N, int bid)
{
  const int t  = threadIdx.x;                 // 0..511
  const int nt = N >> 9;
  const int n  = ((bid % nt) << 9) + t;
  const int k0 = (bid / nt) << 6;
#pragma unroll
  for (int kb = 0; kb < 64; kb += 8) {
    bf16x8 o;
#pragma unroll
    for (int j = 0; j < 8; ++j)
      o[j] = (bf16_t)W[(long)(k0 + kb + j)*N + n];
    *(bf16x8*)&wT[(long)n*K + k0 + kb] = o;
  }
}

// ---- column sums: out[col] = sum_k W[k][col]; 512 cols per block ----------
__device__ __forceinline__ void csum512_body(const float* __restrict__ W,
    float* __restrict__ out, int K, int N, int bid)
{
  const int n = bid*512 + threadIdx.x;
  float s0 = 0.f, s1 = 0.f, s2 = 0.f, s3 = 0.f;
  for (int k = 0; k < K; k += 4) {
    s0 += W[(long)k*N + n];
    s1 += W[(long)(k+1)*N + n];
    s2 += W[(long)(k+2)*N + n];
    s3 += W[(long)(k+3)*N + n];
  }
  out[n] = (s0 + s1) + (s2 + s3);
}

// prologue: layer-0 QKV weights (96 cvt blocks) + cs3 (6 blocks)
__global__ __launch_bounds__(512) void prep0(const float* __restrict__ wq,
    const float* __restrict__ wk, const float* __restrict__ wv,
    bf16_t* __restrict__ wT3, float* __restrict__ cs3)
{
  const int b = blockIdx.x;
  if (b < 96) {
    const int sel = b >> 5;
    const float* W = sel == 0 ? wq : sel == 1 ? wk : wv;
    wcvtNL_body(W, wT3 + (size_t)sel*HID*HID, HID, HID, b & 31);
  } else {
    const int col = (b - 96)*512 + threadIdx.x;
    const int sel = col >> 10, n = col & 1023;
    const float* W = sel == 0 ? wq : sel == 1 ? wk : wv;
    float s = 0.f;
    for (int k = 0; k < HID; ++k) s += W[(long)k*HID + n];
    cs3[col] = s;
  }
}

// ====== bf16 MFMA GEMM, 128x256 tile, BK=64, 8 waves, 32x32x16, LN-fold ====
// MODE 3: out = bf16( rstd*acc + (bias - mean*rstd*cs[col]) )          (QKV)
// MODE 4: out = bf16( relu(same) )                                     (FFN1)
// MODE 5: out = bf16( acc + bias + (res-mean)*rstd ); LN partials      (wo/FFN2)
// PREP 0: none; 1: Wo-cvt(32)+cs1(8); 2: W1-cvt(128);
// PREP 3: W2-cvt(128) [+ next QKV-cvt(96) + cs3(6) if haveNext]
// Prep blocks occupy [0,P); gemm blocks are blockIdx.x - P.
template<int MODE, int PREP>
__global__ __launch_bounds__(512, 4)
void gemmW(const bf16_t* __restrict__ A, const bf16_t* __restrict__ Bt,
           const float* __restrict__ ba, const float* __restrict__ bb,
           const float* __restrict__ bc, const float* __restrict__ cs,
           const float* __restrict__ stats, const bf16_t* __restrict__ res,
           bf16_t* __restrict__ outB, float* __restrict__ part,
           int M, int N, int K, int P,
           const float* __restrict__ pw0, bf16_t* __restrict__ pd0,
           const float* __restrict__ pw1, const float* __restrict__ pw2,
           const float* __restrict__ pw3, bf16_t* __restrict__ pd1,
           float* __restrict__ pf0)
{
  __shared__ bf16_t As[128][64];
  __shared__ bf16_t Bs[256][64];
  __shared__ float  rs[512], rq[512];
  const int tid = threadIdx.x;

  if (PREP > 0 && (int)blockIdx.x < P) {
    const int b = blockIdx.x;
    if (PREP == 1) {
      if (b < 32) wcvtNL_body(pw0, pd0, 1024, 1024, b);          // Wo
      else        csum512_body(pw1, pf0, 1024, 4096, b - 32);    // cs1 of W1
    } else if (PREP == 2) {
      wcvtNL_body(pw0, pd0, 1024, 4096, b);                      // W1
    } else if (PREP == 3) {
      if (b < 128)      wcvtNL_body(pw0, pd0, 4096, 1024, b);    // W2
      else if (b < 160) wcvtNL_body(pw1, pd1, 1024, 1024, b-128);
      else if (b < 192) wcvtNL_body(pw2, pd1 + (size_t)HID*HID, 1024, 1024, b-160);
      else if (b < 224) wcvtNL_body(pw3, pd1 + (size_t)2*HID*HID, 1024, 1024, b-192);
      else {                                                     // cs3
        const int col = (b - 224)*512 + tid;
        const int sel = col >> 10, n = col & 1023;
        const float* W = sel == 0 ? pw1 : sel == 1 ? pw2 : pw3;
        float s = 0.f;
        for (int k = 0; k < HID; ++k) s += W[(long)k*HID + n];
        pf0[col] = s;
      }
    }
    return;
  }
  const int gbid = blockIdx.x - P;

  const int w = tid >> 6, l = tid & 63;
  const int wm = w >> 2, wn = w & 3;
  const int lr = l & 31, hi = l >> 5;

  const int nbn = N >> 8;
  const int nwg = gridDim.x - P;
  const int q8 = nwg >> 3, r8 = nwg & 7;
  const int xcd = gbid & 7, bidx = gbid >> 3;
  const int wg = (xcd < r8 ? xcd*(q8+1) : r8*(q8+1) + (xcd-r8)*q8) + bidx;
  const long bm = wg / nbn, bn = wg % nbn;
  const long rA0 = bm << 7, rB0 = bn << 8;

  const int srow   = tid >> 3;
  const int schunk = (((tid & 7) ^ ((tid >> 3) & 7)) << 3);
  const int ldsw   = (tid >> 6) << 10;

  f32x16 a00 = {0}, a01 = {0}, a10 = {0}, a11 = {0};

#define STG_TILE(kt) do { \
    const long kb_ = (long)(kt)*64 + schunk; \
    gload_lds16(A  + (rA0 + srow)*(long)K + kb_,        (char*)As + ldsw); \
    gload_lds16(A  + (rA0 + 64 + srow)*(long)K + kb_,   (char*)As + 8192 + ldsw); \
    gload_lds16(Bt + (rB0 + srow)*(long)K + kb_,        (char*)Bs + ldsw); \
    gload_lds16(Bt + (rB0 + 64 + srow)*(long)K + kb_,   (char*)Bs + 8192 + ldsw); \
    gload_lds16(Bt + (rB0 + 128 + srow)*(long)K + kb_,  (char*)Bs + 16384 + ldsw); \
    gload_lds16(Bt + (rB0 + 192 + srow)*(long)K + kb_,  (char*)Bs + 24576 + ldsw); \
  } while (0)
#define FRA(mt, kk) (*(const bf16x8*)((const char*)As + (wm*64 + (mt)*32 + lr)*128 + \
                      ((((kk)*2 + hi) ^ (l & 7)) << 4)))
#define FRB(nt, kk) (*(const bf16x8*)((const char*)Bs + (wn*64 + (nt)*32 + lr)*128 + \
                      ((((kk)*2 + hi) ^ (l & 7)) << 4)))

  const int nk = K >> 6;
  for (int t = 0; t < nk; ++t) {
    __syncthreads();
    STG_TILE(t);
    __syncthreads();
#pragma unroll
    for (int kk = 0; kk < 4; ++kk) {
      bf16x8 fa0 = FRA(0, kk), fa1 = FRA(1, kk);
      bf16x8 fb0 = FRB(0, kk), fb1 = FRB(1, kk);
      a00 = __builtin_amdgcn_mfma_f32_32x32x16_bf16(fa0, fb0, a00, 0, 0, 0);
      a01 = __builtin_amdgcn_mfma_f32_32x32x16_bf16(fa0, fb1, a01, 0, 0, 0);
      a10 = __builtin_amdgcn_mfma_f32_32x32x16_bf16(fa1, fb0, a10, 0, 0, 0);
      a11 = __builtin_amdgcn_mfma_f32_32x32x16_bf16(fa1, fb1, a11, 0, 0, 0);
    }
  }
#undef STG_TILE
#undef FRA
#undef FRB

  const float mS = stats[0], rS = stats[1];
  const bool q3 = (N == 3072);
  float ls = 0.f, lsq = 0.f;
  const long rowT = rA0 + wm*64 + 4*hi;
  const long colT = rB0 + wn*64 + lr;
#pragma unroll
  for (int nt = 0; nt < 2; ++nt) {
    const long col = colT + nt*32;
    float bv;
    if (MODE == 3 && q3)
      bv = col < 1024 ? ba[col] : col < 2048 ? bb[col - 1024] : bc[col - 2048];
    else
      bv = ba[col];
    float beta = 0.f;
    if (MODE == 3 || MODE == 4) beta = bv - mS*rS*cs[col];
#pragma unroll
    for (int mt = 0; mt < 2; ++mt) {
      const f32x16 acc = mt == 0 ? (nt == 0 ? a00 : a01) : (nt == 0 ? a10 : a11);
#pragma unroll
      for (int r = 0; r < 16; ++r) {
        const long row = rowT + mt*32 + (r & 3) + 8*(r >> 2);
        const long off = row*(long)N + col;
        float v;
        if (MODE == 3)      v = fmaf(acc[r], rS, beta);
        else if (MODE == 4) v = fmaxf(fmaf(acc[r], rS, beta), 0.f);
        else {
          v = acc[r] + bv + ((float)res[off] - mS)*rS;
          ls += v; lsq += v*v;
        }
        outB[off] = (bf16_t)v;
      }
    }
  }
  if (MODE == 5) {
    rs[tid] = ls; rq[tid] = lsq;
    __syncthreads();
    for (int o = 256; o > 0; o >>= 1) {
      if (tid < o) { rs[tid] += rs[tid+o]; rq[tid] += rq[tid+o]; }
      __syncthreads();
    }
    if (tid == 0) { part[2*gbid] = rs[0]; part[2*gbid + 1] = rq[0]; }
  }
}

// ---------------- attention: one block per (b, head), standalone -----------
__global__ __launch_bounds__(256) void attn_k(
    const bf16_t* __restrict__ qkv, bf16_t* __restrict__ ob)
{
  __shared__ __align__(16) char smem[64*128*2*2 + 64*64*4 + 64*4];
  bf16_t* Qc = (bf16_t*)smem;
  bf16_t* Kc = (bf16_t*)(smem + 16384);
  bf16_t* Vc = (bf16_t*)smem;                  // aliases Qc (phase-disjoint)
  float*  E    = (float*)(smem + 32768);
  float*  Rinv = (float*)(smem + 49152);

  const int tid  = threadIdx.x;
  const int head = blockIdx.x & 7, b = blockIdx.x >> 3;
  const long rbase = (long)head*32 + b;

  const int ti = tid >> 2, g = tid & 3;
  const int lr  = tid >> 2;
  const int lp0 = (tid & 3) * 4;

  float eacc[16];
#pragma unroll
  for (int j = 0; j < 16; ++j) eacc[j] = 0.f;

  for (int kc = 0; kc < HID; kc += 128) {
    __syncthreads();
    const bf16_t* qrow = qkv + (lr*256 + rbase)*QKVS + kc;
    const bf16_t* krow = qkv + (lr*256 + rbase)*QKVS + 1024 + kc;
#pragma unroll
    for (int i = 0; i < 4; ++i) {
      const int p = lp0 + i;
      const int src = (p ^ (lr & 7)) * 8;
      *(uint4*)&Qc[lr*128 + p*8] = *(const uint4*)&qrow[src];
      *(uint4*)&Kc[lr*128 + p*8] = *(const uint4*)&krow[src];
    }
    __syncthreads();
    for (int e8 = 0; e8 < 16; ++e8) {
      const int qp = e8 ^ (ti & 7);
      bf16x8 qv = *(bf16x8*)&Qc[ti*128 + qp*8];
      float qf[8];
#pragma unroll
      for (int u = 0; u < 8; ++u) qf[u] = (float)qv[u];
#pragma unroll
      for (int j = 0; j < 16; ++j) {
        const int s  = j*4 + g;
        const int kp = e8 ^ (s & 7);
        bf16x8 kv = *(bf16x8*)&Kc[s*128 + kp*8];
        float a = eacc[j];
#pragma unroll
        for (int u = 0; u < 8; ++u) a += qf[u] * (float)kv[u];
        eacc[j] = a;
      }
    }
  }
  const float scale = 0.0883883476483184f;     // 1/sqrt(128)
  float mx = -1e30f;
#pragma unroll
  for (int j = 0; j < 16; ++j) { eacc[j] *= scale; mx = fmaxf(mx, eacc[j]); }
  mx = fmaxf(mx, __shfl_xor(mx, 1));
  mx = fmaxf(mx, __shfl_xor(mx, 2));
  float sum = 0.f;
#pragma unroll
  for (int j = 0; j < 16; ++j) {
    const float pj = __expf(eacc[j] - mx);
    E[(j*4 + g)*64 + ti] = pj;
    sum += pj;
  }
  sum += __shfl_xor(sum, 1);
  sum += __shfl_xor(sum, 2);
  if (g == 0) Rinv[ti] = 1.f / sum;
  __syncthreads();

  const int lane = tid & 63, wq_ = tid >> 6;
  const float rv = Rinv[lane];
  const long orow = (long)lane*256 + b*8 + head;
  for (int fc = 0; fc < HID; fc += 128) {
    __syncthreads();
    const bf16_t* vrow = qkv + (lr*256 + rbase)*QKVS + 2048 + fc;
#pragma unroll
    for (int i = 0; i < 4; ++i) {
      const int p = lp0 + i;
      *(uint4*)&Vc[lr*128 + p*8] = *(const uint4*)&vrow[p*8];
    }
    __syncthreads();
    float vacc[32];
#pragma unroll
    for (int u = 0; u < 32; ++u) vacc[u] = 0.f;
    for (int s = 0; s < 64; ++s) {
      const float pp = E[s*64 + lane];
#pragma unroll
      for (int u = 0; u < 4; ++u) {
        bf16x8 vv = *(bf16x8*)&Vc[s*128 + wq_*32 + u*8];
#pragma unroll
        for (int t8 = 0; t8 < 8; ++t8) vacc[u*8 + t8] += pp * (float)vv[t8];
      }
    }
#pragma unroll
    for (int u = 0; u < 4; ++u) {
      bf16x8 ov;
#pragma unroll
      for (int t8 = 0; t8 < 8; ++t8) ov[t8] = (bf16_t)(vacc[u*8 + t8] * rv);
      *(bf16x8*)&ob[orow*HID + fc + wq_*32 + u*8] = ov;
    }
  }
}

// -------- LN stage 2: sum per-block partials (np pairs) -> mean/rstd -------
__global__ __launch_bounds__(256) void reduce2(const float* __restrict__ part,
                                               float* __restrict__ stats, int np)
{
  __shared__ double sh[256], sh2[256];
  const int tid = threadIdx.x;
  double s = 0.0, s2 = 0.0;
  for (int i = tid; i < np; i += 256) { s += part[2*i]; s2 += part[2*i + 1]; }
  sh[tid] = s; sh2[tid] = s2; __syncthreads();
  for (int o = 128; o > 0; o >>= 1) {
    if (tid < o) { sh[tid] += sh[tid+o]; sh2[tid] += sh2[tid+o]; }
    __syncthreads();
  }
  if (tid == 0) {
    const double n = (double)NTOT;
    const double mean = sh[0] / n;
    const double var  = sh2[0] / n - mean*mean;
    stats[0] = (float)mean;
    stats[1] = (float)(1.0 / sqrt(var + 1e-5));
  }
}

// -------- final: d_out(f32) = (t2_raw - mean)*rstd -------------------------
__global__ __launch_bounds__(256) void final_norm(const bf16_t* __restrict__ t,
    const float* __restrict__ stats, float* __restrict__ out)
{
  const float m = stats[0], r = stats[1];
  const long n8 = NTOT / 8;
  for (long i = (long)blockIdx.x*blockDim.x + threadIdx.x; i < n8;
       i += (long)gridDim.x*blockDim.x) {
    bf16x8 v = ((const bf16x8*)t)[i];
    float4 o0 = {((float)v[0]-m)*r, ((float)v[1]-m)*r, ((float)v[2]-m)*r, ((float)v[3]-m)*r};
    float4 o1 = {((float)v[4]-m)*r, ((float)v[5]-m)*r, ((float)v[6]-m)*r, ((float)v[7]-m)*r};
    ((float4*)out)[2*i]   = o0;
    ((float4*)out)[2*i+1] = o1;
  }
}

// ---------------------------------------------------------------------------
extern "C" void kernel_launch(void* const* d_in, const int* in_sizes, int n_in,
                              void* d_out, int out_size, void* d_ws, size_t ws_size,
                              hipStream_t stream)
{
  const int*   x    = (const int*)  d_in[0];
  const float* emb  = (const float*)d_in[1];
  const float* pos  = (const float*)d_in[2];
  const float* wq_a = (const float*)d_in[3];
  const float* bq_a = (const float*)d_in[4];
  const float* wk_a = (const float*)d_in[5];
  const float* bk_a = (const float*)d_in[6];
  const float* wv_a = (const float*)d_in[7];
  const float* bv_a = (const float*)d_in[8];
  const float* wo_a = (const float*)d_in[9];
  const float* bo_a = (const float*)d_in[10];
  const float* w1_a = (const float*)d_in[11];
  const float* b1_a = (const float*)d_in[12];
  const float* w2_a = (const float*)d_in[13];
  const float* b2_a = (const float*)d_in[14];

  char* p = (char*)d_ws;
  auto take = [&](size_t n) { char* r = p; p += (n + 255) & ~(size_t)255; return r; };
  bf16_t* hb   = (bf16_t*)take(NTOT*2);                 // raw hidden (rolling)
  bf16_t* U    = (bf16_t*)take((size_t)NROW*FFD*2);     // 128 MB union
  bf16_t* qkv  = U;                                     // NROW x 3072
  bf16_t* attb = U + 3*NTOT;
  bf16_t* ffb  = U;                                     // overlays qkv (dead)
  bf16_t* wTo  = (bf16_t*)take((size_t)HID*HID*2);
  bf16_t* wT1  = (bf16_t*)take((size_t)HID*FFD*2);
  bf16_t* wT2  = (bf16_t*)take((size_t)HID*FFD*2);
  bf16_t* wT3  = (bf16_t*)take((size_t)3*HID*HID*2);
  float*  cs1  = (float*) take(FFD*4);
  float*  cs3  = (float*) take(QKVS*4);
  float*  part = (float*) take(4096*4);
  float*  stId = (float*) take(256);
  float*  st1  = (float*) take(256);
  float*  st2  = (float*) take(256);

  const int gQKV = (NROW/128)*(QKVS/256);   // 1536
  const int gH   = (NROW/128)*(HID/256);    // 512
  const int gF   = (NROW/128)*(FFD/256);    // 2048

  embed_k<<<NROW, 256, 0, stream>>>(x, emb, pos, hb, stId);
  prep0<<<102, 512, 0, stream>>>(wq_a, wk_a, wv_a, wT3, cs3);

  for (int i = 0; i < 6; ++i) {
    const float* Bq = bq_a + (size_t)i*HID;
    const float* Bk = bk_a + (size_t)i*HID;
    const float* Bv = bv_a + (size_t)i*HID;
    const float* Wo = wo_a + (size_t)i*HID*HID;  const float* Bo = bo_a + (size_t)i*HID;
    const float* W1 = w1_a + (size_t)i*HID*FFD;  const float* B1 = b1_a + (size_t)i*FFD;
    const float* W2 = w2_a + (size_t)i*FFD*HID;  const float* B2 = b2_a + (size_t)i*HID;
    const float* stIn = (i == 0) ? stId : st2;
    const int haveNext = (i < 5);
    const float* Wqn = wq_a + (size_t)(i+1)*HID*HID;
    const float* Wkn = wk_a + (size_t)(i+1)*HID*HID;
    const float* Wvn = wv_a + (size_t)(i+1)*HID*HID;

    // QKV projection (LN-fold); carries Wo-cvt + cs1
    gemmW<3,1><<<40 + gQKV, 512, 0, stream>>>(
        hb, wT3, Bq, Bk, Bv, cs3, stIn, nullptr, qkv, nullptr,
        NROW, QKVS, HID, 40, Wo, wTo, W1, nullptr, nullptr, nullptr, cs1);

    attn_k<<<256, 256, 0, stream>>>(qkv, attb);

    // wo projection + residual fold + LN partials; carries W1-cvt
    gemmW<5,2><<<128 + gH, 512, 0, stream>>>(
        attb, wTo, Bo, Bo, Bo, nullptr, stIn, hb, hb, part,
        NROW, HID, HID, 128, W1, wT1, nullptr, nullptr, nullptr, nullptr, nullptr);
    reduce2<<<1, 256, 0, stream>>>(part, st1, gH);

    // FFN1 (LN-fold + relu); carries W2-cvt + next QKV-cvt + cs3
    const int P3 = haveNext ? 230 : 128;
    gemmW<4,3><<<P3 + gF, 512, 0, stream>>>(
        hb, wT1, B1, B1, B1, cs1, st1, nullptr, ffb, nullptr,
        NROW, FFD, HID, P3, W2, wT2, Wqn, Wkn, Wvn, wT3, cs3);

    // FFN2 + residual fold + LN partials
    gemmW<5,0><<<gH, 512, 0, stream>>>(
        ffb, wT2, B2, B2, B2, nullptr, st1, hb, hb, part,
        NROW, HID, FFD, 0, nullptr, nullptr, nullptr, nullptr, nullptr, nullptr, nullptr);
    reduce2<<<1, 256, 0, stream>>>(part, st2, gH);
  }

  final_norm<<<2048, 256, 0, stream>>>(hb, st2, (float*)d_out);
}

// Round 9
// 4053.522 us; speedup vs baseline: 1.0356x; 1.0356x over previous
//
#include <hip/hip_runtime.h>
#include <hip/hip_bf16.h>
#include <stdint.h>

typedef __bf16 bf16_t;
typedef __bf16 bf16x8 __attribute__((ext_vector_type(8)));
typedef __bf16 bf16x4 __attribute__((ext_vector_type(4)));
typedef float  f32x16 __attribute__((ext_vector_type(16)));

#define SEQ   512
#define BATCH 32
#define HID   1024
#define FFD   4096
#define NROW  (SEQ*BATCH)          /* 16384 rows */
#define NTOT  ((long)NROW*HID)     /* 16,777,216 */
#define QKVS  3072

typedef __attribute__((address_space(3))) uint32_t lds_u32;
typedef __attribute__((address_space(1))) const uint32_t glb_u32;

__device__ __forceinline__ void gload_lds16(const void* g, void* l) {
  glb_u32* gp = reinterpret_cast<glb_u32*>(reinterpret_cast<uintptr_t>(g));
  lds_u32* lp = reinterpret_cast<lds_u32*>(reinterpret_cast<uintptr_t>(l));
  __builtin_amdgcn_global_load_lds(gp, lp, 16, 0, 0);
}

// ------------- embedding: hb = bf16(emb[x]*32 + pos[s]); init stId ---------
__global__ __launch_bounds__(256) void embed_k(const int* __restrict__ x,
    const float* __restrict__ emb, const float* __restrict__ pos,
    bf16_t* __restrict__ hb, float* __restrict__ stId)
{
  if (blockIdx.x == 0 && threadIdx.x == 0) { stId[0] = 0.f; stId[1] = 1.f; }
  const long row = blockIdx.x;           // row = s*32 + b
  const int  s   = (int)(row >> 5);
  const long idx = x[row];
  const int  t   = threadIdx.x;
  float4 e  = ((const float4*)(emb + idx*HID))[t];
  float4 pv = ((const float4*)(pos + (long)s*HID))[t];
  bf16x4 ob = {(bf16_t)(e.x*32.f+pv.x), (bf16_t)(e.y*32.f+pv.y),
               (bf16_t)(e.z*32.f+pv.z), (bf16_t)(e.w*32.f+pv.w)};
  *(bf16x4*)(hb + row*HID + (long)t*4) = ob;
}

// ---- LDS-free weight convert+transpose (512 threads/block) ----------------
// wT[n][k] = bf16(W[k][n]); block tile: 512 n-cols x 64 k.
__device__ __forceinline__ void wcvtNL_body(const float* __restrict__ W,
    bf16_t* __restrict__ wT, int K, int N, int bid)
{
  const int t  = threadIdx.x;                 // 0..511
  const int nt = N >> 9;
  const int n  = ((bid % nt) << 9) + t;
  const int k0 = (bid / nt) << 6;
#pragma unroll
  for (int kb = 0; kb < 64; kb += 8) {
    bf16x8 o;
#pragma unroll
    for (int j = 0; j < 8; ++j)
      o[j] = (bf16_t)W[(long)(k0 + kb + j)*N + n];
    *(bf16x8*)&wT[(long)n*K + k0 + kb] = o;
  }
}

// ---- column sums: out[col] = sum_k W[k][col]; 512 cols per block ----------
__device__ __forceinline__ void csum512_body(const float* __restrict__ W,
    float* __restrict__ out, int K, int N, int bid)
{
  const int n = bid*512 + threadIdx.x;
  float s0 = 0.f, s1 = 0.f, s2 = 0.f, s3 = 0.f;
  for (int k = 0; k < K; k += 4) {
    s0 += W[(long)k*N + n];
    s1 += W[(long)(k+1)*N + n];
    s2 += W[(long)(k+2)*N + n];
    s3 += W[(long)(k+3)*N + n];
  }
  out[n] = (s0 + s1) + (s2 + s3);
}

// prologue: layer-0 QKV weights (96 cvt blocks) + cs3 (6 blocks)
__global__ __launch_bounds__(512) void prep0(const float* __restrict__ wq,
    const float* __restrict__ wk, const float* __restrict__ wv,
    bf16_t* __restrict__ wT3, float* __restrict__ cs3)
{
  const int b = blockIdx.x;
  if (b < 96) {
    const int sel = b >> 5;
    const float* W = sel == 0 ? wq : sel == 1 ? wk : wv;
    wcvtNL_body(W, wT3 + (size_t)sel*HID*HID, HID, HID, b & 31);
  } else {
    const int col = (b - 96)*512 + threadIdx.x;
    const int sel = col >> 10, n = col & 1023;
    const float* W = sel == 0 ? wq : sel == 1 ? wk : wv;
    float s = 0.f;
    for (int k = 0; k < HID; ++k) s += W[(long)k*HID + n];
    cs3[col] = s;
  }
}

// ---- per-layer prep: Wo/W1/W2 cvt + cs1 [+ next QKV cvt + cs3] ------------
__global__ __launch_bounds__(512) void prep_k(
    const float* __restrict__ Wo, bf16_t* __restrict__ wTo,
    const float* __restrict__ W1, bf16_t* __restrict__ wT1, float* __restrict__ cs1,
    const float* __restrict__ W2, bf16_t* __restrict__ wT2,
    const float* __restrict__ Wq, const float* __restrict__ Wk,
    const float* __restrict__ Wv, bf16_t* __restrict__ wT3,
    float* __restrict__ cs3)
{
  const int b = blockIdx.x;
  if (b < 32)        wcvtNL_body(Wo, wTo, HID, HID, b);
  else if (b < 160)  wcvtNL_body(W1, wT1, HID, FFD, b - 32);
  else if (b < 288)  wcvtNL_body(W2, wT2, FFD, HID, b - 160);
  else if (b < 296)  csum512_body(W1, cs1, HID, FFD, b - 288);
  else if (b < 392) {
    const int i = b - 296, sel = i >> 5;
    const float* W = sel == 0 ? Wq : sel == 1 ? Wk : Wv;
    wcvtNL_body(W, wT3 + (size_t)sel*HID*HID, HID, HID, i & 31);
  } else {
    const int col = (b - 392)*512 + threadIdx.x;
    const int sel = col >> 10, n = col & 1023;
    const float* W = sel == 0 ? Wq : sel == 1 ? Wk : Wv;
    float s = 0.f;
    for (int k = 0; k < HID; ++k) s += W[(long)k*HID + n];
    cs3[col] = s;
  }
}

// ====== bf16 MFMA GEMM, 128x256 tile, BK=64, 8 waves, 32x32x16, LN-fold ====
// MODE 3: out = bf16( rstd*acc + (bias - mean*rstd*cs[col]) )          (QKV)
// MODE 4: out = bf16( relu(same) )                                     (FFN1)
// MODE 5: out = bf16( acc + bias + (res-mean)*rstd ); LN partials      (wo/FFN2)
template<int MODE>
__global__ __launch_bounds__(512, 4)
void gemmW(const bf16_t* __restrict__ A, const bf16_t* __restrict__ Bt,
           const float* __restrict__ ba, const float* __restrict__ bb,
           const float* __restrict__ bc, const float* __restrict__ cs,
           const float* __restrict__ stats, const bf16_t* __restrict__ res,
           bf16_t* __restrict__ outB, float* __restrict__ part,
           int M, int N, int K)
{
  __shared__ bf16_t As[128][64];
  __shared__ bf16_t Bs[256][64];
  __shared__ float  rs[512], rq[512];
  const int tid = threadIdx.x;
  const int w = tid >> 6, l = tid & 63;
  const int wm = w >> 2, wn = w & 3;
  const int lr = l & 31, hi = l >> 5;

  const int nbn = N >> 8;
  const int nwg = gridDim.x;
  const int q8 = nwg >> 3, r8 = nwg & 7;
  const int xcd = blockIdx.x & 7, bidx = blockIdx.x >> 3;
  const int wg = (xcd < r8 ? xcd*(q8+1) : r8*(q8+1) + (xcd-r8)*q8) + bidx;
  const long bm = wg / nbn, bn = wg % nbn;
  const long rA0 = bm << 7, rB0 = bn << 8;

  const int srow   = tid >> 3;
  const int schunk = (((tid & 7) ^ ((tid >> 3) & 7)) << 3);
  const int ldsw   = (tid >> 6) << 10;

  f32x16 a00 = {0}, a01 = {0}, a10 = {0}, a11 = {0};

#define STG_TILE(kt) do { \
    const long kb_ = (long)(kt)*64 + schunk; \
    gload_lds16(A  + (rA0 + srow)*(long)K + kb_,        (char*)As + ldsw); \
    gload_lds16(A  + (rA0 + 64 + srow)*(long)K + kb_,   (char*)As + 8192 + ldsw); \
    gload_lds16(Bt + (rB0 + srow)*(long)K + kb_,        (char*)Bs + ldsw); \
    gload_lds16(Bt + (rB0 + 64 + srow)*(long)K + kb_,   (char*)Bs + 8192 + ldsw); \
    gload_lds16(Bt + (rB0 + 128 + srow)*(long)K + kb_,  (char*)Bs + 16384 + ldsw); \
    gload_lds16(Bt + (rB0 + 192 + srow)*(long)K + kb_,  (char*)Bs + 24576 + ldsw); \
  } while (0)
#define FRA(mt, kk) (*(const bf16x8*)((const char*)As + (wm*64 + (mt)*32 + lr)*128 + \
                      ((((kk)*2 + hi) ^ (l & 7)) << 4)))
#define FRB(nt, kk) (*(const bf16x8*)((const char*)Bs + (wn*64 + (nt)*32 + lr)*128 + \
                      ((((kk)*2 + hi) ^ (l & 7)) << 4)))

  const int nk = K >> 6;
  for (int t = 0; t < nk; ++t) {
    __syncthreads();
    STG_TILE(t);
    __syncthreads();
#pragma unroll
    for (int kk = 0; kk < 4; ++kk) {
      bf16x8 fa0 = FRA(0, kk), fa1 = FRA(1, kk);
      bf16x8 fb0 = FRB(0, kk), fb1 = FRB(1, kk);
      a00 = __builtin_amdgcn_mfma_f32_32x32x16_bf16(fa0, fb0, a00, 0, 0, 0);
      a01 = __builtin_amdgcn_mfma_f32_32x32x16_bf16(fa0, fb1, a01, 0, 0, 0);
      a10 = __builtin_amdgcn_mfma_f32_32x32x16_bf16(fa1, fb0, a10, 0, 0, 0);
      a11 = __builtin_amdgcn_mfma_f32_32x32x16_bf16(fa1, fb1, a11, 0, 0, 0);
    }
  }
#undef STG_TILE
#undef FRA
#undef FRB

  const float mS = stats[0], rS = stats[1];
  const bool q3 = (N == 3072);
  float ls = 0.f, lsq = 0.f;
  const long rowT = rA0 + wm*64 + 4*hi;
  const long colT = rB0 + wn*64 + lr;
#pragma unroll
  for (int nt = 0; nt < 2; ++nt) {
    const long col = colT + nt*32;
    float bv;
    if (MODE == 3 && q3)
      bv = col < 1024 ? ba[col] : col < 2048 ? bb[col - 1024] : bc[col - 2048];
    else
      bv = ba[col];
    float beta = 0.f;
    if (MODE == 3 || MODE == 4) beta = bv - mS*rS*cs[col];
#pragma unroll
    for (int mt = 0; mt < 2; ++mt) {
      const f32x16 acc = mt == 0 ? (nt == 0 ? a00 : a01) : (nt == 0 ? a10 : a11);
#pragma unroll
      for (int r = 0; r < 16; ++r) {
        const long row = rowT + mt*32 + (r & 3) + 8*(r >> 2);
        const long off = row*(long)N + col;
        float v;
        if (MODE == 3)      v = fmaf(acc[r], rS, beta);
        else if (MODE == 4) v = fmaxf(fmaf(acc[r], rS, beta), 0.f);
        else {
          v = acc[r] + bv + ((float)res[off] - mS)*rS;
          ls += v; lsq += v*v;
        }
        outB[off] = (bf16_t)v;
      }
    }
  }
  if (MODE == 5) {
    rs[tid] = ls; rq[tid] = lsq;
    __syncthreads();
    for (int o = 256; o > 0; o >>= 1) {
      if (tid < o) { rs[tid] += rs[tid+o]; rq[tid] += rq[tid+o]; }
      __syncthreads();
    }
    if (tid == 0) { part[2*blockIdx.x] = rs[0]; part[2*blockIdx.x + 1] = rq[0]; }
  }
}

// ---------------- attention: one block per (b, head), 512 threads ----------
// in_row(t) = t*256 + head*32 + b;  out_row(t) = t*256 + b*8 + head
__global__ __launch_bounds__(512) void attn_k(
    const bf16_t* __restrict__ qkv, bf16_t* __restrict__ ob)
{
  __shared__ __align__(16) char smem[64*128*2*2 + 64*64*4 + 64*4];
  bf16_t* Qc = (bf16_t*)smem;                  // 16 KB (src-swizzled slots)
  bf16_t* Kc = (bf16_t*)(smem + 16384);        // 16 KB
  bf16_t* Vc = (bf16_t*)smem;                  // aliases Qc (phase-disjoint)
  float*  E    = (float*)(smem + 32768);       // 16 KB, idx^(s&7) swizzle
  float*  Rinv = (float*)(smem + 49152);

  const int tid  = threadIdx.x;
  const int head = blockIdx.x & 7, b = blockIdx.x >> 3;
  const long rbase = (long)head*32 + b;

  const int ti = tid >> 3, g = tid & 7;        // 8 threads per ti
  const int lr = tid >> 3;                     // staging row 0..63

  float eacc[8];
#pragma unroll
  for (int j = 0; j < 8; ++j) eacc[j] = 0.f;

  for (int kc = 0; kc < HID; kc += 128) {
    __syncthreads();
    const bf16_t* qrow = qkv + (lr*256 + rbase)*QKVS + kc;
    const bf16_t* krow = qkv + (lr*256 + rbase)*QKVS + 1024 + kc;
#pragma unroll
    for (int i = 0; i < 2; ++i) {
      const int p = i*8 + g;                   // bank-spread slot
      const int src = (p ^ (lr & 7)) * 8;
      *(uint4*)&Qc[lr*128 + p*8] = *(const uint4*)&qrow[src];
      *(uint4*)&Kc[lr*128 + p*8] = *(const uint4*)&krow[src];
    }
    __syncthreads();
    for (int e8 = 0; e8 < 16; ++e8) {
      const int qp = e8 ^ (ti & 7);
      bf16x8 qv = *(bf16x8*)&Qc[ti*128 + qp*8];
      float qf[8];
#pragma unroll
      for (int u = 0; u < 8; ++u) qf[u] = (float)qv[u];
#pragma unroll
      for (int j = 0; j < 8; ++j) {
        const int s  = j*8 + g;
        const int kp = e8 ^ (s & 7);
        bf16x8 kv = *(bf16x8*)&Kc[s*128 + kp*8];
        float a = eacc[j];
#pragma unroll
        for (int u = 0; u < 8; ++u) a += qf[u] * (float)kv[u];
        eacc[j] = a;
      }
    }
  }
  // softmax over s for each ti (8 threads per ti)
  const float scale = 0.0883883476483184f;     // 1/sqrt(128)
  float mx = -1e30f;
#pragma unroll
  for (int j = 0; j < 8; ++j) { eacc[j] *= scale; mx = fmaxf(mx, eacc[j]); }
  mx = fmaxf(mx, __shfl_xor(mx, 1));
  mx = fmaxf(mx, __shfl_xor(mx, 2));
  mx = fmaxf(mx, __shfl_xor(mx, 4));
  float sum = 0.f;
#pragma unroll
  for (int j = 0; j < 8; ++j) {
    const float pj = __expf(eacc[j] - mx);
    const int s = j*8 + g;
    E[s*64 + (ti ^ (s & 7))] = pj;             // bank-spread store
    sum += pj;
  }
  sum += __shfl_xor(sum, 1);
  sum += __shfl_xor(sum, 2);
  sum += __shfl_xor(sum, 4);
  if (g == 0) Rinv[ti] = 1.f / sum;
  __syncthreads();

  // PV: lane = output row t, wave (8) = feature eighth (16 cols of 128)
  const int lane = tid & 63, w8 = tid >> 6;
  const float rv = Rinv[lane];
  const long orow = (long)lane*256 + b*8 + head;
  for (int fc = 0; fc < HID; fc += 128) {
    __syncthreads();
    const bf16_t* vrow = qkv + (lr*256 + rbase)*QKVS + 2048 + fc;
#pragma unroll
    for (int i = 0; i < 2; ++i) {
      const int p = i*8 + g;
      *(uint4*)&Vc[lr*128 + p*8] = *(const uint4*)&vrow[p*8];
    }
    __syncthreads();
    float vacc[16];
#pragma unroll
    for (int u = 0; u < 16; ++u) vacc[u] = 0.f;
    for (int s = 0; s < 64; ++s) {
      const float pp = E[s*64 + (lane ^ (s & 7))];
#pragma unroll
      for (int u = 0; u < 2; ++u) {
        bf16x8 vv = *(bf16x8*)&Vc[s*128 + w8*16 + u*8];
#pragma unroll
        for (int t8 = 0; t8 < 8; ++t8) vacc[u*8 + t8] += pp * (float)vv[t8];
      }
    }
#pragma unroll
    for (int u = 0; u < 2; ++u) {
      bf16x8 ov;
#pragma unroll
      for (int t8 = 0; t8 < 8; ++t8) ov[t8] = (bf16_t)(vacc[u*8 + t8] * rv);
      *(bf16x8*)&ob[orow*HID + fc + w8*16 + u*8] = ov;
    }
  }
}

// -------- LN stage 2: sum per-block partials (np pairs) -> mean/rstd -------
__global__ __launch_bounds__(256) void reduce2(const float* __restrict__ part,
                                               float* __restrict__ stats, int np)
{
  __shared__ double sh[256], sh2[256];
  const int tid = threadIdx.x;
  double s = 0.0, s2 = 0.0;
  for (int i = tid; i < np; i += 256) { s += part[2*i]; s2 += part[2*i + 1]; }
  sh[tid] = s; sh2[tid] = s2; __syncthreads();
  for (int o = 128; o > 0; o >>= 1) {
    if (tid < o) { sh[tid] += sh[tid+o]; sh2[tid] += sh2[tid+o]; }
    __syncthreads();
  }
  if (tid == 0) {
    const double n = (double)NTOT;
    const double mean = sh[0] / n;
    const double var  = sh2[0] / n - mean*mean;
    stats[0] = (float)mean;
    stats[1] = (float)(1.0 / sqrt(var + 1e-5));
  }
}

// -------- final: d_out(f32) = (t2_raw - mean)*rstd -------------------------
__global__ __launch_bounds__(256) void final_norm(const bf16_t* __restrict__ t,
    const float* __restrict__ stats, float* __restrict__ out)
{
  const float m = stats[0], r = stats[1];
  const long n8 = NTOT / 8;
  for (long i = (long)blockIdx.x*blockDim.x + threadIdx.x; i < n8;
       i += (long)gridDim.x*blockDim.x) {
    bf16x8 v = ((const bf16x8*)t)[i];
    float4 o0 = {((float)v[0]-m)*r, ((float)v[1]-m)*r, ((float)v[2]-m)*r, ((float)v[3]-m)*r};
    float4 o1 = {((float)v[4]-m)*r, ((float)v[5]-m)*r, ((float)v[6]-m)*r, ((float)v[7]-m)*r};
    ((float4*)out)[2*i]   = o0;
    ((float4*)out)[2*i+1] = o1;
  }
}

// ---------------------------------------------------------------------------
extern "C" void kernel_launch(void* const* d_in, const int* in_sizes, int n_in,
                              void* d_out, int out_size, void* d_ws, size_t ws_size,
                              hipStream_t stream)
{
  const int*   x    = (const int*)  d_in[0];
  const float* emb  = (const float*)d_in[1];
  const float* pos  = (const float*)d_in[2];
  const float* wq_a = (const float*)d_in[3];
  const float* bq_a = (const float*)d_in[4];
  const float* wk_a = (const float*)d_in[5];
  const float* bk_a = (const float*)d_in[6];
  const float* wv_a = (const float*)d_in[7];
  const float* bv_a = (const float*)d_in[8];
  const float* wo_a = (const float*)d_in[9];
  const float* bo_a = (const float*)d_in[10];
  const float* w1_a = (const float*)d_in[11];
  const float* b1_a = (const float*)d_in[12];
  const float* w2_a = (const float*)d_in[13];
  const float* b2_a = (const float*)d_in[14];

  char* p = (char*)d_ws;
  auto take = [&](size_t n) { char* r = p; p += (n + 255) & ~(size_t)255; return r; };
  bf16_t* hb   = (bf16_t*)take(NTOT*2);                 // raw hidden (rolling)
  bf16_t* U    = (bf16_t*)take((size_t)NROW*FFD*2);     // 128 MB union
  bf16_t* qkv  = U;                                     // NROW x 3072
  bf16_t* attb = U + 3*NTOT;
  bf16_t* ffb  = U;                                     // overlays qkv (dead)
  bf16_t* wTo  = (bf16_t*)take((size_t)HID*HID*2);
  bf16_t* wT1  = (bf16_t*)take((size_t)HID*FFD*2);
  bf16_t* wT2  = (bf16_t*)take((size_t)HID*FFD*2);
  bf16_t* wT3  = (bf16_t*)take((size_t)3*HID*HID*2);
  float*  cs1  = (float*) take(FFD*4);
  float*  cs3  = (float*) take(QKVS*4);
  float*  part = (float*) take(4096*4);
  float*  stId = (float*) take(256);
  float*  st1  = (float*) take(256);
  float*  st2  = (float*) take(256);

  const int gQKV = (NROW/128)*(QKVS/256);   // 1536
  const int gH   = (NROW/128)*(HID/256);    // 512
  const int gF   = (NROW/128)*(FFD/256);    // 2048

  embed_k<<<NROW, 256, 0, stream>>>(x, emb, pos, hb, stId);
  prep0<<<102, 512, 0, stream>>>(wq_a, wk_a, wv_a, wT3, cs3);

  for (int i = 0; i < 6; ++i) {
    const float* Bq = bq_a + (size_t)i*HID;
    const float* Bk = bk_a + (size_t)i*HID;
    const float* Bv = bv_a + (size_t)i*HID;
    const float* Wo = wo_a + (size_t)i*HID*HID;  const float* Bo = bo_a + (size_t)i*HID;
    const float* W1 = w1_a + (size_t)i*HID*FFD;  const float* B1 = b1_a + (size_t)i*FFD;
    const float* W2 = w2_a + (size_t)i*FFD*HID;  const float* B2 = b2_a + (size_t)i*HID;
    const float* stIn = (i == 0) ? stId : st2;
    const int haveNext = (i < 5);
    const float* Wqn = wq_a + (size_t)(i+1)*HID*HID;
    const float* Wkn = wk_a + (size_t)(i+1)*HID*HID;
    const float* Wvn = wv_a + (size_t)(i+1)*HID*HID;

    // QKV projection (LN-fold into epilogue)
    gemmW<3><<<gQKV, 512, 0, stream>>>(hb, wT3, Bq, Bk, Bv, cs3, stIn,
                                       nullptr, qkv, nullptr, NROW, QKVS, HID);

    attn_k<<<256, 512, 0, stream>>>(qkv, attb);

    // standalone LDS-free weight prep for this layer (+ next-layer QKV)
    prep_k<<<haveNext ? 398 : 296, 512, 0, stream>>>(
        Wo, wTo, W1, wT1, cs1, W2, wT2, Wqn, Wkn, Wvn, wT3, cs3);

    // wo projection + residual fold + LN partials
    gemmW<5><<<gH, 512, 0, stream>>>(attb, wTo, Bo, Bo, Bo, nullptr, stIn,
                                     hb, hb, part, NROW, HID, HID);
    reduce2<<<1, 256, 0, stream>>>(part, st1, gH);

    // FFN1 (LN-fold + relu)
    gemmW<4><<<gF, 512, 0, stream>>>(hb, wT1, B1, B1, B1, cs1, st1,
                                     nullptr, ffb, nullptr, NROW, FFD, HID);

    // FFN2 + residual fold + LN partials
    gemmW<5><<<gH, 512, 0, stream>>>(ffb, wT2, B2, B2, B2, nullptr, st1,
                                     hb, hb, part, NROW, HID, FFD);
    reduce2<<<1, 256, 0, stream>>>(part, st2, gH);
  }

  final_norm<<<2048, 256, 0, stream>>>(hb, st2, (float*)d_out);
}

// Round 10
// 3451.538 us; speedup vs baseline: 1.2162x; 1.1744x over previous
//
#include <hip/hip_runtime.h>
#include <hip/hip_bf16.h>
#include <stdint.h>

typedef __bf16 bf16_t;
typedef __bf16 bf16x8 __attribute__((ext_vector_type(8)));
typedef __bf16 bf16x4 __attribute__((ext_vector_type(4)));
typedef float  f32x4  __attribute__((ext_vector_type(4)));
typedef float  f32x16 __attribute__((ext_vector_type(16)));

#define SEQ   512
#define BATCH 32
#define HID   1024
#define FFD   4096
#define NROW  (SEQ*BATCH)          /* 16384 rows */
#define NTOT  ((long)NROW*HID)     /* 16,777,216 */
#define QKVS  3072

typedef __attribute__((address_space(3))) uint32_t lds_u32;
typedef __attribute__((address_space(1))) const uint32_t glb_u32;

__device__ __forceinline__ void gload_lds16(const void* g, void* l) {
  glb_u32* gp = reinterpret_cast<glb_u32*>(reinterpret_cast<uintptr_t>(g));
  lds_u32* lp = reinterpret_cast<lds_u32*>(reinterpret_cast<uintptr_t>(l));
  __builtin_amdgcn_global_load_lds(gp, lp, 16, 0, 0);
}

// ------------- embedding: hb = bf16(emb[x]*32 + pos[s]); init stId ---------
__global__ __launch_bounds__(256) void embed_k(const int* __restrict__ x,
    const float* __restrict__ emb, const float* __restrict__ pos,
    bf16_t* __restrict__ hb, float* __restrict__ stId)
{
  if (blockIdx.x == 0 && threadIdx.x == 0) { stId[0] = 0.f; stId[1] = 1.f; }
  const long row = blockIdx.x;           // row = s*32 + b
  const int  s   = (int)(row >> 5);
  const long idx = x[row];
  const int  t   = threadIdx.x;
  float4 e  = ((const float4*)(emb + idx*HID))[t];
  float4 pv = ((const float4*)(pos + (long)s*HID))[t];
  bf16x4 ob = {(bf16_t)(e.x*32.f+pv.x), (bf16_t)(e.y*32.f+pv.y),
               (bf16_t)(e.z*32.f+pv.z), (bf16_t)(e.w*32.f+pv.w)};
  *(bf16x4*)(hb + row*HID + (long)t*4) = ob;
}

// ---- LDS-free weight convert+transpose (512 threads/block) ----------------
__device__ __forceinline__ void wcvtNL_body(const float* __restrict__ W,
    bf16_t* __restrict__ wT, int K, int N, int bid)
{
  const int t  = threadIdx.x;                 // 0..511
  const int nt = N >> 9;
  const int n  = ((bid % nt) << 9) + t;
  const int k0 = (bid / nt) << 6;
#pragma unroll
  for (int kb = 0; kb < 64; kb += 8) {
    bf16x8 o;
#pragma unroll
    for (int j = 0; j < 8; ++j)
      o[j] = (bf16_t)W[(long)(k0 + kb + j)*N + n];
    *(bf16x8*)&wT[(long)n*K + k0 + kb] = o;
  }
}

// ---- column sums: out[col] = sum_k W[k][col]; 512 cols per block ----------
__device__ __forceinline__ void csum512_body(const float* __restrict__ W,
    float* __restrict__ out, int K, int N, int bid)
{
  const int n = bid*512 + threadIdx.x;
  float s0 = 0.f, s1 = 0.f, s2 = 0.f, s3 = 0.f;
  for (int k = 0; k < K; k += 4) {
    s0 += W[(long)k*N + n];
    s1 += W[(long)(k+1)*N + n];
    s2 += W[(long)(k+2)*N + n];
    s3 += W[(long)(k+3)*N + n];
  }
  out[n] = (s0 + s1) + (s2 + s3);
}

// prologue: layer-0 QKV weights (96 cvt blocks) + cs3 (6 blocks)
__global__ __launch_bounds__(512) void prep0(const float* __restrict__ wq,
    const float* __restrict__ wk, const float* __restrict__ wv,
    bf16_t* __restrict__ wT3, float* __restrict__ cs3)
{
  const int b = blockIdx.x;
  if (b < 96) {
    const int sel = b >> 5;
    const float* W = sel == 0 ? wq : sel == 1 ? wk : wv;
    wcvtNL_body(W, wT3 + (size_t)sel*HID*HID, HID, HID, b & 31);
  } else {
    const int col = (b - 96)*512 + threadIdx.x;
    const int sel = col >> 10, n = col & 1023;
    const float* W = sel == 0 ? wq : sel == 1 ? wk : wv;
    float s = 0.f;
    for (int k = 0; k < HID; ++k) s += W[(long)k*HID + n];
    cs3[col] = s;
  }
}

// ---- per-layer prep: Wo/W1/W2 cvt + cs1 [+ next QKV cvt + cs3] ------------
__global__ __launch_bounds__(512) void prep_k(
    const float* __restrict__ Wo, bf16_t* __restrict__ wTo,
    const float* __restrict__ W1, bf16_t* __restrict__ wT1, float* __restrict__ cs1,
    const float* __restrict__ W2, bf16_t* __restrict__ wT2,
    const float* __restrict__ Wq, const float* __restrict__ Wk,
    const float* __restrict__ Wv, bf16_t* __restrict__ wT3,
    float* __restrict__ cs3)
{
  const int b = blockIdx.x;
  if (b < 32)        wcvtNL_body(Wo, wTo, HID, HID, b);
  else if (b < 160)  wcvtNL_body(W1, wT1, HID, FFD, b - 32);
  else if (b < 288)  wcvtNL_body(W2, wT2, FFD, HID, b - 160);
  else if (b < 296)  csum512_body(W1, cs1, HID, FFD, b - 288);
  else if (b < 392) {
    const int i = b - 296, sel = i >> 5;
    const float* W = sel == 0 ? Wq : sel == 1 ? Wk : Wv;
    wcvtNL_body(W, wT3 + (size_t)sel*HID*HID, HID, HID, i & 31);
  } else {
    const int col = (b - 392)*512 + threadIdx.x;
    const int sel = col >> 10, n = col & 1023;
    const float* W = sel == 0 ? Wq : sel == 1 ? Wk : Wv;
    float s = 0.f;
    for (int k = 0; k < HID; ++k) s += W[(long)k*HID + n];
    cs3[col] = s;
  }
}

// ====== bf16 MFMA GEMM, 128x256 tile, BK=64, 8 waves, 32x32x16, LN-fold ====
// MODE 3: out = bf16( rstd*acc + (bias - mean*rstd*cs[col]) )          (QKV)
// MODE 4: out = bf16( relu(same) )                                     (FFN1)
// MODE 5: out = bf16( acc + bias + (res-mean)*rstd ); LN partials      (wo/FFN2)
template<int MODE>
__global__ __launch_bounds__(512, 4)
void gemmW(const bf16_t* __restrict__ A, const bf16_t* __restrict__ Bt,
           const float* __restrict__ ba, const float* __restrict__ bb,
           const float* __restrict__ bc, const float* __restrict__ cs,
           const float* __restrict__ stats, const bf16_t* __restrict__ res,
           bf16_t* __restrict__ outB, float* __restrict__ part,
           int M, int N, int K)
{
  __shared__ bf16_t As[128][64];
  __shared__ bf16_t Bs[256][64];
  __shared__ float  rs[512], rq[512];
  const int tid = threadIdx.x;
  const int w = tid >> 6, l = tid & 63;
  const int wm = w >> 2, wn = w & 3;
  const int lr = l & 31, hi = l >> 5;

  const int nbn = N >> 8;
  const int nwg = gridDim.x;
  const int q8 = nwg >> 3, r8 = nwg & 7;
  const int xcd = blockIdx.x & 7, bidx = blockIdx.x >> 3;
  const int wg = (xcd < r8 ? xcd*(q8+1) : r8*(q8+1) + (xcd-r8)*q8) + bidx;
  const long bm = wg / nbn, bn = wg % nbn;
  const long rA0 = bm << 7, rB0 = bn << 8;

  const int srow   = tid >> 3;
  const int schunk = (((tid & 7) ^ ((tid >> 3) & 7)) << 3);
  const int ldsw   = (tid >> 6) << 10;

  f32x16 a00 = {0}, a01 = {0}, a10 = {0}, a11 = {0};

#define STG_TILE(kt) do { \
    const long kb_ = (long)(kt)*64 + schunk; \
    gload_lds16(A  + (rA0 + srow)*(long)K + kb_,        (char*)As + ldsw); \
    gload_lds16(A  + (rA0 + 64 + srow)*(long)K + kb_,   (char*)As + 8192 + ldsw); \
    gload_lds16(Bt + (rB0 + srow)*(long)K + kb_,        (char*)Bs + ldsw); \
    gload_lds16(Bt + (rB0 + 64 + srow)*(long)K + kb_,   (char*)Bs + 8192 + ldsw); \
    gload_lds16(Bt + (rB0 + 128 + srow)*(long)K + kb_,  (char*)Bs + 16384 + ldsw); \
    gload_lds16(Bt + (rB0 + 192 + srow)*(long)K + kb_,  (char*)Bs + 24576 + ldsw); \
  } while (0)
#define FRA(mt, kk) (*(const bf16x8*)((const char*)As + (wm*64 + (mt)*32 + lr)*128 + \
                      ((((kk)*2 + hi) ^ (l & 7)) << 4)))
#define FRB(nt, kk) (*(const bf16x8*)((const char*)Bs + (wn*64 + (nt)*32 + lr)*128 + \
                      ((((kk)*2 + hi) ^ (l & 7)) << 4)))

  const int nk = K >> 6;
  for (int t = 0; t < nk; ++t) {
    __syncthreads();
    STG_TILE(t);
    __syncthreads();
#pragma unroll
    for (int kk = 0; kk < 4; ++kk) {
      bf16x8 fa0 = FRA(0, kk), fa1 = FRA(1, kk);
      bf16x8 fb0 = FRB(0, kk), fb1 = FRB(1, kk);
      a00 = __builtin_amdgcn_mfma_f32_32x32x16_bf16(fa0, fb0, a00, 0, 0, 0);
      a01 = __builtin_amdgcn_mfma_f32_32x32x16_bf16(fa0, fb1, a01, 0, 0, 0);
      a10 = __builtin_amdgcn_mfma_f32_32x32x16_bf16(fa1, fb0, a10, 0, 0, 0);
      a11 = __builtin_amdgcn_mfma_f32_32x32x16_bf16(fa1, fb1, a11, 0, 0, 0);
    }
  }
#undef STG_TILE
#undef FRA
#undef FRB

  const float mS = stats[0], rS = stats[1];
  const bool q3 = (N == 3072);
  float ls = 0.f, lsq = 0.f;
  const long rowT = rA0 + wm*64 + 4*hi;
  const long colT = rB0 + wn*64 + lr;
#pragma unroll
  for (int nt = 0; nt < 2; ++nt) {
    const long col = colT + nt*32;
    float bv;
    if (MODE == 3 && q3)
      bv = col < 1024 ? ba[col] : col < 2048 ? bb[col - 1024] : bc[col - 2048];
    else
      bv = ba[col];
    float beta = 0.f;
    if (MODE == 3 || MODE == 4) beta = bv - mS*rS*cs[col];
#pragma unroll
    for (int mt = 0; mt < 2; ++mt) {
      const f32x16 acc = mt == 0 ? (nt == 0 ? a00 : a01) : (nt == 0 ? a10 : a11);
#pragma unroll
      for (int r = 0; r < 16; ++r) {
        const long row = rowT + mt*32 + (r & 3) + 8*(r >> 2);
        const long off = row*(long)N + col;
        float v;
        if (MODE == 3)      v = fmaf(acc[r], rS, beta);
        else if (MODE == 4) v = fmaxf(fmaf(acc[r], rS, beta), 0.f);
        else {
          v = acc[r] + bv + ((float)res[off] - mS)*rS;
          ls += v; lsq += v*v;
        }
        outB[off] = (bf16_t)v;
      }
    }
  }
  if (MODE == 5) {
    rs[tid] = ls; rq[tid] = lsq;
    __syncthreads();
    for (int o = 256; o > 0; o >>= 1) {
      if (tid < o) { rs[tid] += rs[tid+o]; rq[tid] += rq[tid+o]; }
      __syncthreads();
    }
    if (tid == 0) { part[2*blockIdx.x] = rs[0]; part[2*blockIdx.x + 1] = rq[0]; }
  }
}

// ========== MFMA attention: one block per (b, head), 4 waves ===============
// in_row(t) = t*256 + head*32 + b;  out_row(t) = t*256 + b*8 + head
// Phase 1: S[64][64] = Q.K^T via 16x16x32 MFMA (wave w -> S row-tile w).
// Softmax in-register (C layout: col=lane&15, row=(lane>>4)*4+j; row lives in
// 16 lanes -> shfl_xor reduce). rinv folded into bf16 P (LDS, slot-swizzled).
// Phase 2: O = P.V; V transposed into LDS [f][s] during staging; O chunked
// 128 features at a time, staged through LDS for coalesced stores.
__global__ __launch_bounds__(256) void attn_m(
    const bf16_t* __restrict__ qkv, bf16_t* __restrict__ ob)
{
  __shared__ __align__(16) bf16_t QK[2][8192];   // 32 KB: Q|K, later V^T|O
  __shared__ __align__(16) bf16_t Ps[64*64];     // 8 KB
  bf16_t* Vs = &QK[0][0];                        // [128][64] phase 2
  bf16_t* Os = &QK[1][0];                        // [64][128] phase 2

  const int tid = threadIdx.x;
  const int w = tid >> 6, l = tid & 63;
  const int fr = l & 15, kq = l >> 4;
  const int head = blockIdx.x & 7, b = blockIdx.x >> 3;
  const long rbase = (long)head*32 + b;

  const int lr  = tid >> 2;                      // staging row 0..63
  const int sslot = (tid & 15) ^ (tid >> 4);     // pre-swizzled Q/K src slot

  f32x4 accS[4] = {{0,0,0,0},{0,0,0,0},{0,0,0,0},{0,0,0,0}};

  // ---------------- phase 1: S = Q.K^T over K=1024 -------------------------
  for (int kc = 0; kc < HID; kc += 128) {
    __syncthreads();
#pragma unroll
    for (int i = 0; i < 4; ++i) {
      const int r = i*16 + (tid >> 4);           // LDS row; r&15 == tid>>4
      const long gq = ((long)r*256 + rbase)*QKVS + kc + sslot*8;
      gload_lds16(qkv + gq,        (char*)&QK[0][0] + i*4096 + w*1024);
      gload_lds16(qkv + gq + 1024, (char*)&QK[1][0] + i*4096 + w*1024);
    }
    __syncthreads();                             // drains vmcnt (compiler)
#pragma unroll
    for (int kk = 0; kk < 4; ++kk) {
      const int ra = w*16 + fr;
      bf16x8 a = *(const bf16x8*)&QK[0][ra*128 + (((kk*4 + kq) ^ fr) << 3)];
#pragma unroll
      for (int n = 0; n < 4; ++n) {
        const int rb = n*16 + fr;
        bf16x8 bv = *(const bf16x8*)&QK[1][rb*128 + (((kk*4 + kq) ^ fr) << 3)];
        accS[n] = __builtin_amdgcn_mfma_f32_16x16x32_bf16(a, bv, accS[n], 0, 0, 0);
      }
    }
  }

  // ---------------- softmax (rows live in 16-lane groups) ------------------
  const float scale = 0.08838834764831843f;      // 1/sqrt(128)
  float pj[4][4];
#pragma unroll
  for (int j = 0; j < 4; ++j) {
    float m = fmaxf(fmaxf(accS[0][j], accS[1][j]), fmaxf(accS[2][j], accS[3][j]));
    m = fmaxf(m, __shfl_xor(m, 1));
    m = fmaxf(m, __shfl_xor(m, 2));
    m = fmaxf(m, __shfl_xor(m, 4));
    m = fmaxf(m, __shfl_xor(m, 8));
    m *= scale;
    float s = 0.f;
#pragma unroll
    for (int n = 0; n < 4; ++n) { pj[n][j] = __expf(accS[n][j]*scale - m); s += pj[n][j]; }
    s += __shfl_xor(s, 1);
    s += __shfl_xor(s, 2);
    s += __shfl_xor(s, 4);
    s += __shfl_xor(s, 8);
    const float rv = 1.f / s;
#pragma unroll
    for (int n = 0; n < 4; ++n) pj[n][j] *= rv;
  }
  // store normalized P as bf16 (slot-swizzled for A-frag reads)
#pragma unroll
  for (int n = 0; n < 4; ++n)
#pragma unroll
    for (int j = 0; j < 4; ++j) {
      const int r = w*16 + kq*4 + j;
      const int cpos = n*16 + fr;
      Ps[r*64 + (((cpos >> 3) ^ (r & 7)) << 3) + (cpos & 7)] = (bf16_t)pj[n][j];
    }
  __syncthreads();                               // P visible; QK free

  // ---------------- phase 2: O = P.V, 128-feature chunks -------------------
  const long orow = (long)lr*256 + b*8 + head;
  for (int fc = 0; fc < HID; fc += 128) {
    // stage V transposed: Vs[f][s], s-slots swizzled by f&7
    const bf16_t* vrow = qkv + ((long)lr*256 + rbase)*QKVS + 2048 + fc;
#pragma unroll
    for (int i = 0; i < 4; ++i) {
      const int f0 = (tid & 3)*8 + i*32;
      uint4 vv = *(const uint4*)&vrow[f0];
      const bf16_t* ve = (const bf16_t*)&vv;
#pragma unroll
      for (int j = 0; j < 8; ++j) {
        const int f = f0 + j;
        Vs[f*64 + (((lr >> 3) ^ (f & 7)) << 3) + (lr & 7)] = ve[j];
      }
    }
    __syncthreads();
    // MFMA: wave w -> O rows w*16..+15, all 128 features of this chunk
    const int ra = w*16 + fr;
    bf16x8 a0 = *(const bf16x8*)&Ps[ra*64 + ((kq       ^ (ra & 7)) << 3)];
    bf16x8 a1 = *(const bf16x8*)&Ps[ra*64 + (((4 + kq) ^ (ra & 7)) << 3)];
    f32x4 accO[8];
#pragma unroll
    for (int nt = 0; nt < 8; ++nt) {
      const int f = nt*16 + fr;
      bf16x8 b0 = *(const bf16x8*)&Vs[f*64 + ((kq       ^ (f & 7)) << 3)];
      bf16x8 b1 = *(const bf16x8*)&Vs[f*64 + (((4 + kq) ^ (f & 7)) << 3)];
      accO[nt] = __builtin_amdgcn_mfma_f32_16x16x32_bf16(a0, b0, (f32x4){0.f,0.f,0.f,0.f}, 0, 0, 0);
      accO[nt] = __builtin_amdgcn_mfma_f32_16x16x32_bf16(a1, b1, accO[nt], 0, 0, 0);
    }
    // write O chunk to LDS (bf16, slot-swizzled), then coalesced global store
#pragma unroll
    for (int nt = 0; nt < 8; ++nt)
#pragma unroll
      for (int j = 0; j < 4; ++j) {
        const int r = w*16 + kq*4 + j;
        const int cpos = nt*16 + fr;
        Os[r*128 + (((cpos >> 3) ^ (r & 7)) << 3) + (cpos & 7)] = (bf16_t)accO[nt][j];
      }
    __syncthreads();
#pragma unroll
    for (int i = 0; i < 4; ++i) {
      const int p = (tid & 3)*4 + i;             // logical 16B slot 0..15
      uint4 vv = *(const uint4*)&Os[lr*128 + ((p ^ (lr & 7)) << 3)];
      *(uint4*)&ob[orow*HID + fc + p*8] = vv;
    }
  }
}

// -------- LN stage 2: sum per-block partials (np pairs) -> mean/rstd -------
__global__ __launch_bounds__(256) void reduce2(const float* __restrict__ part,
                                               float* __restrict__ stats, int np)
{
  __shared__ double sh[256], sh2[256];
  const int tid = threadIdx.x;
  double s = 0.0, s2 = 0.0;
  for (int i = tid; i < np; i += 256) { s += part[2*i]; s2 += part[2*i + 1]; }
  sh[tid] = s; sh2[tid] = s2; __syncthreads();
  for (int o = 128; o > 0; o >>= 1) {
    if (tid < o) { sh[tid] += sh[tid+o]; sh2[tid] += sh2[tid+o]; }
    __syncthreads();
  }
  if (tid == 0) {
    const double n = (double)NTOT;
    const double mean = sh[0] / n;
    const double var  = sh2[0] / n - mean*mean;
    stats[0] = (float)mean;
    stats[1] = (float)(1.0 / sqrt(var + 1e-5));
  }
}

// -------- final: d_out(f32) = (t2_raw - mean)*rstd -------------------------
__global__ __launch_bounds__(256) void final_norm(const bf16_t* __restrict__ t,
    const float* __restrict__ stats, float* __restrict__ out)
{
  const float m = stats[0], r = stats[1];
  const long n8 = NTOT / 8;
  for (long i = (long)blockIdx.x*blockDim.x + threadIdx.x; i < n8;
       i += (long)gridDim.x*blockDim.x) {
    bf16x8 v = ((const bf16x8*)t)[i];
    float4 o0 = {((float)v[0]-m)*r, ((float)v[1]-m)*r, ((float)v[2]-m)*r, ((float)v[3]-m)*r};
    float4 o1 = {((float)v[4]-m)*r, ((float)v[5]-m)*r, ((float)v[6]-m)*r, ((float)v[7]-m)*r};
    ((float4*)out)[2*i]   = o0;
    ((float4*)out)[2*i+1] = o1;
  }
}

// ---------------------------------------------------------------------------
extern "C" void kernel_launch(void* const* d_in, const int* in_sizes, int n_in,
                              void* d_out, int out_size, void* d_ws, size_t ws_size,
                              hipStream_t stream)
{
  const int*   x    = (const int*)  d_in[0];
  const float* emb  = (const float*)d_in[1];
  const float* pos  = (const float*)d_in[2];
  const float* wq_a = (const float*)d_in[3];
  const float* bq_a = (const float*)d_in[4];
  const float* wk_a = (const float*)d_in[5];
  const float* bk_a = (const float*)d_in[6];
  const float* wv_a = (const float*)d_in[7];
  const float* bv_a = (const float*)d_in[8];
  const float* wo_a = (const float*)d_in[9];
  const float* bo_a = (const float*)d_in[10];
  const float* w1_a = (const float*)d_in[11];
  const float* b1_a = (const float*)d_in[12];
  const float* w2_a = (const float*)d_in[13];
  const float* b2_a = (const float*)d_in[14];

  char* p = (char*)d_ws;
  auto take = [&](size_t n) { char* r = p; p += (n + 255) & ~(size_t)255; return r; };
  bf16_t* hb   = (bf16_t*)take(NTOT*2);                 // raw hidden (rolling)
  bf16_t* U    = (bf16_t*)take((size_t)NROW*FFD*2);     // 128 MB union
  bf16_t* qkv  = U;                                     // NROW x 3072
  bf16_t* attb = U + 3*NTOT;
  bf16_t* ffb  = U;                                     // overlays qkv (dead)
  bf16_t* wTo  = (bf16_t*)take((size_t)HID*HID*2);
  bf16_t* wT1  = (bf16_t*)take((size_t)HID*FFD*2);
  bf16_t* wT2  = (bf16_t*)take((size_t)HID*FFD*2);
  bf16_t* wT3  = (bf16_t*)take((size_t)3*HID*HID*2);
  float*  cs1  = (float*) take(FFD*4);
  float*  cs3  = (float*) take(QKVS*4);
  float*  part = (float*) take(4096*4);
  float*  stId = (float*) take(256);
  float*  st1  = (float*) take(256);
  float*  st2  = (float*) take(256);

  const int gQKV = (NROW/128)*(QKVS/256);   // 1536
  const int gH   = (NROW/128)*(HID/256);    // 512
  const int gF   = (NROW/128)*(FFD/256);    // 2048

  embed_k<<<NROW, 256, 0, stream>>>(x, emb, pos, hb, stId);
  prep0<<<102, 512, 0, stream>>>(wq_a, wk_a, wv_a, wT3, cs3);

  for (int i = 0; i < 6; ++i) {
    const float* Bq = bq_a + (size_t)i*HID;
    const float* Bk = bk_a + (size_t)i*HID;
    const float* Bv = bv_a + (size_t)i*HID;
    const float* Wo = wo_a + (size_t)i*HID*HID;  const float* Bo = bo_a + (size_t)i*HID;
    const float* W1 = w1_a + (size_t)i*HID*FFD;  const float* B1 = b1_a + (size_t)i*FFD;
    const float* W2 = w2_a + (size_t)i*FFD*HID;  const float* B2 = b2_a + (size_t)i*HID;
    const float* stIn = (i == 0) ? stId : st2;
    const int haveNext = (i < 5);
    const float* Wqn = wq_a + (size_t)(i+1)*HID*HID;
    const float* Wkn = wk_a + (size_t)(i+1)*HID*HID;
    const float* Wvn = wv_a + (size_t)(i+1)*HID*HID;

    // QKV projection (LN-fold into epilogue)
    gemmW<3><<<gQKV, 512, 0, stream>>>(hb, wT3, Bq, Bk, Bv, cs3, stIn,
                                       nullptr, qkv, nullptr, NROW, QKVS, HID);

    attn_m<<<256, 256, 0, stream>>>(qkv, attb);

    // standalone LDS-free weight prep for this layer (+ next-layer QKV)
    prep_k<<<haveNext ? 398 : 296, 512, 0, stream>>>(
        Wo, wTo, W1, wT1, cs1, W2, wT2, Wqn, Wkn, Wvn, wT3, cs3);

    // wo projection + residual fold + LN partials
    gemmW<5><<<gH, 512, 0, stream>>>(attb, wTo, Bo, Bo, Bo, nullptr, stIn,
                                     hb, hb, part, NROW, HID, HID);
    reduce2<<<1, 256, 0, stream>>>(part, st1, gH);

    // FFN1 (LN-fold + relu)
    gemmW<4><<<gF, 512, 0, stream>>>(hb, wT1, B1, B1, B1, cs1, st1,
                                     nullptr, ffb, nullptr, NROW, FFD, HID);

    // FFN2 + residual fold + LN partials
    gemmW<5><<<gH, 512, 0, stream>>>(ffb, wT2, B2, B2, B2, nullptr, st1,
                                     hb, hb, part, NROW, HID, FFD);
    reduce2<<<1, 256, 0, stream>>>(part, st2, gH);
  }

  final_norm<<<2048, 256, 0, stream>>>(hb, st2, (float*)d_out);
}

// Round 11
// 3405.249 us; speedup vs baseline: 1.2327x; 1.0136x over previous
//
#include <hip/hip_runtime.h>
#include <hip/hip_bf16.h>
#include <stdint.h>

typedef __bf16 bf16_t;
typedef __bf16 bf16x8 __attribute__((ext_vector_type(8)));
typedef __bf16 bf16x4 __attribute__((ext_vector_type(4)));
typedef float  f32x4  __attribute__((ext_vector_type(4)));
typedef float  f32x16 __attribute__((ext_vector_type(16)));

#define SEQ   512
#define BATCH 32
#define HID   1024
#define FFD   4096
#define NROW  (SEQ*BATCH)          /* 16384 rows */
#define NTOT  ((long)NROW*HID)     /* 16,777,216 */
#define QKVS  3072

typedef __attribute__((address_space(3))) uint32_t lds_u32;
typedef __attribute__((address_space(1))) const uint32_t glb_u32;

__device__ __forceinline__ void gload_lds16(const void* g, void* l) {
  glb_u32* gp = reinterpret_cast<glb_u32*>(reinterpret_cast<uintptr_t>(g));
  lds_u32* lp = reinterpret_cast<lds_u32*>(reinterpret_cast<uintptr_t>(l));
  __builtin_amdgcn_global_load_lds(gp, lp, 16, 0, 0);
}
#define BAR() asm volatile("s_barrier" ::: "memory")

// ------------- embedding: hb = bf16(emb[x]*32 + pos[s]) --------------------
__global__ __launch_bounds__(256) void embed_k(const int* __restrict__ x,
    const float* __restrict__ emb, const float* __restrict__ pos,
    bf16_t* __restrict__ hb)
{
  const long row = blockIdx.x;           // row = s*32 + b
  const int  s   = (int)(row >> 5);
  const long idx = x[row];
  const int  t   = threadIdx.x;
  float4 e  = ((const float4*)(emb + idx*HID))[t];
  float4 pv = ((const float4*)(pos + (long)s*HID))[t];
  bf16x4 ob = {(bf16_t)(e.x*32.f+pv.x), (bf16_t)(e.y*32.f+pv.y),
               (bf16_t)(e.z*32.f+pv.z), (bf16_t)(e.w*32.f+pv.w)};
  *(bf16x4*)(hb + row*HID + (long)t*4) = ob;
}

// ---- inline stats: reduce np partial (sum,sumsq) pairs -> mean, rstd ------
// nthr = blockDim; uses shd scratch (>= 16 doubles). All threads return same.
__device__ __forceinline__ void stats_reduce(const float* __restrict__ part,
    int np, double* shd, float& mS, float& rS, int nthr)
{
  if (np == 0) { mS = 0.f; rS = 1.f; return; }
  const int tid = threadIdx.x;
  double s = 0.0, s2 = 0.0;
  for (int i = tid; i < np; i += nthr) { s += (double)part[2*i]; s2 += (double)part[2*i+1]; }
#pragma unroll
  for (int o = 1; o < 64; o <<= 1) { s += __shfl_xor(s, o); s2 += __shfl_xor(s2, o); }
  __syncthreads();                      // LDS scratch safe to overwrite
  const int w = tid >> 6, nw = nthr >> 6;
  if ((tid & 63) == 0) { shd[w] = s; shd[8 + w] = s2; }
  __syncthreads();
  double ts = 0.0, ts2 = 0.0;
  for (int i = 0; i < nw; ++i) { ts += shd[i]; ts2 += shd[8 + i]; }
  const double mean = ts / (double)NTOT;
  const double var  = ts2 / (double)NTOT - mean*mean;
  mS = (float)mean;
  rS = (float)(1.0 / sqrt(var + 1e-5));
}

// ---- LDS-free weight convert+transpose (512 threads/block) ----------------
__device__ __forceinline__ void wcvtNL_body(const float* __restrict__ W,
    bf16_t* __restrict__ wT, int K, int N, int bid)
{
  const int t  = threadIdx.x;                 // 0..511
  const int nt = N >> 9;
  const int n  = ((bid % nt) << 9) + t;
  const int k0 = (bid / nt) << 6;
#pragma unroll
  for (int kb = 0; kb < 64; kb += 8) {
    bf16x8 o;
#pragma unroll
    for (int j = 0; j < 8; ++j)
      o[j] = (bf16_t)W[(long)(k0 + kb + j)*N + n];
    *(bf16x8*)&wT[(long)n*K + k0 + kb] = o;
  }
}

// ---- column sums: out[col] = sum_k W[k][col]; 512 cols per block ----------
__device__ __forceinline__ void csum512_body(const float* __restrict__ W,
    float* __restrict__ out, int K, int N, int bid)
{
  const int n = bid*512 + threadIdx.x;
  float s0 = 0.f, s1 = 0.f, s2 = 0.f, s3 = 0.f;
  for (int k = 0; k < K; k += 4) {
    s0 += W[(long)k*N + n];
    s1 += W[(long)(k+1)*N + n];
    s2 += W[(long)(k+2)*N + n];
    s3 += W[(long)(k+3)*N + n];
  }
  out[n] = (s0 + s1) + (s2 + s3);
}

// prologue: layer-0 QKV weights (96 cvt blocks) + cs3 (6 blocks)
__global__ __launch_bounds__(512) void prep0(const float* __restrict__ wq,
    const float* __restrict__ wk, const float* __restrict__ wv,
    bf16_t* __restrict__ wT3, float* __restrict__ cs3)
{
  const int b = blockIdx.x;
  if (b < 96) {
    const int sel = b >> 5;
    const float* W = sel == 0 ? wq : sel == 1 ? wk : wv;
    wcvtNL_body(W, wT3 + (size_t)sel*HID*HID, HID, HID, b & 31);
  } else {
    const int col = (b - 96)*512 + threadIdx.x;
    const int sel = col >> 10, n = col & 1023;
    const float* W = sel == 0 ? wq : sel == 1 ? wk : wv;
    float s = 0.f;
    for (int k = 0; k < HID; ++k) s += W[(long)k*HID + n];
    cs3[col] = s;
  }
}

// ---- per-layer prep: Wo/W1/W2 cvt + cs1 [+ next QKV cvt + cs3] ------------
__global__ __launch_bounds__(512) void prep_k(
    const float* __restrict__ Wo, bf16_t* __restrict__ wTo,
    const float* __restrict__ W1, bf16_t* __restrict__ wT1, float* __restrict__ cs1,
    const float* __restrict__ W2, bf16_t* __restrict__ wT2,
    const float* __restrict__ Wq, const float* __restrict__ Wk,
    const float* __restrict__ Wv, bf16_t* __restrict__ wT3,
    float* __restrict__ cs3)
{
  const int b = blockIdx.x;
  if (b < 32)        wcvtNL_body(Wo, wTo, HID, HID, b);
  else if (b < 160)  wcvtNL_body(W1, wT1, HID, FFD, b - 32);
  else if (b < 288)  wcvtNL_body(W2, wT2, FFD, HID, b - 160);
  else if (b < 296)  csum512_body(W1, cs1, HID, FFD, b - 288);
  else if (b < 392) {
    const int i = b - 296, sel = i >> 5;
    const float* W = sel == 0 ? Wq : sel == 1 ? Wk : Wv;
    wcvtNL_body(W, wT3 + (size_t)sel*HID*HID, HID, HID, i & 31);
  } else {
    const int col = (b - 392)*512 + threadIdx.x;
    const int sel = col >> 10, n = col & 1023;
    const float* W = sel == 0 ? Wq : sel == 1 ? Wk : Wv;
    float s = 0.f;
    for (int k = 0; k < HID; ++k) s += W[(long)k*HID + n];
    cs3[col] = s;
  }
}

// ====== bf16 MFMA GEMM, 128x256 tile, BK=64, 8 waves, 32x32x16, LN-fold ====
// MODE 3: out = bf16( rstd*acc + (bias - mean*rstd*cs[col]) )          (QKV)
// MODE 4: out = bf16( relu(same) )                                     (FFN1)
// MODE 5: out = bf16( acc + bias + (res-mean)*rstd ); LN partials      (wo/FFN2)
// stats come from inline reduction of partIn (npIn pairs); npIn==0 -> identity
template<int MODE>
__global__ __launch_bounds__(512, 4)
void gemmW(const bf16_t* __restrict__ A, const bf16_t* __restrict__ Bt,
           const float* __restrict__ ba, const float* __restrict__ bb,
           const float* __restrict__ bc, const float* __restrict__ cs,
           const float* __restrict__ partIn, int npIn,
           const bf16_t* __restrict__ res,
           bf16_t* __restrict__ outB, float* __restrict__ part,
           int M, int N, int K)
{
  __shared__ bf16_t As[128][64];
  __shared__ bf16_t Bs[256][64];
  __shared__ float  rs[512], rq[512];
  const int tid = threadIdx.x;
  const int w = tid >> 6, l = tid & 63;
  const int wm = w >> 2, wn = w & 3;
  const int lr = l & 31, hi = l >> 5;

  const int nbn = N >> 8;
  const int nwg = gridDim.x;
  const int q8 = nwg >> 3, r8 = nwg & 7;
  const int xcd = blockIdx.x & 7, bidx = blockIdx.x >> 3;
  const int wg = (xcd < r8 ? xcd*(q8+1) : r8*(q8+1) + (xcd-r8)*q8) + bidx;
  const long bm = wg / nbn, bn = wg % nbn;
  const long rA0 = bm << 7, rB0 = bn << 8;

  const int srow   = tid >> 3;
  const int schunk = (((tid & 7) ^ ((tid >> 3) & 7)) << 3);
  const int ldsw   = (tid >> 6) << 10;

  f32x16 a00 = {0}, a01 = {0}, a10 = {0}, a11 = {0};

#define STG_TILE(kt) do { \
    const long kb_ = (long)(kt)*64 + schunk; \
    gload_lds16(A  + (rA0 + srow)*(long)K + kb_,        (char*)As + ldsw); \
    gload_lds16(A  + (rA0 + 64 + srow)*(long)K + kb_,   (char*)As + 8192 + ldsw); \
    gload_lds16(Bt + (rB0 + srow)*(long)K + kb_,        (char*)Bs + ldsw); \
    gload_lds16(Bt + (rB0 + 64 + srow)*(long)K + kb_,   (char*)Bs + 8192 + ldsw); \
    gload_lds16(Bt + (rB0 + 128 + srow)*(long)K + kb_,  (char*)Bs + 16384 + ldsw); \
    gload_lds16(Bt + (rB0 + 192 + srow)*(long)K + kb_,  (char*)Bs + 24576 + ldsw); \
  } while (0)
#define FRA(mt, kk) (*(const bf16x8*)((const char*)As + (wm*64 + (mt)*32 + lr)*128 + \
                      ((((kk)*2 + hi) ^ (l & 7)) << 4)))
#define FRB(nt, kk) (*(const bf16x8*)((const char*)Bs + (wn*64 + (nt)*32 + lr)*128 + \
                      ((((kk)*2 + hi) ^ (l & 7)) << 4)))

  const int nk = K >> 6;
  for (int t = 0; t < nk; ++t) {
    __syncthreads();
    STG_TILE(t);
    __syncthreads();
#pragma unroll
    for (int kk = 0; kk < 4; ++kk) {
      bf16x8 fa0 = FRA(0, kk), fa1 = FRA(1, kk);
      bf16x8 fb0 = FRB(0, kk), fb1 = FRB(1, kk);
      a00 = __builtin_amdgcn_mfma_f32_32x32x16_bf16(fa0, fb0, a00, 0, 0, 0);
      a01 = __builtin_amdgcn_mfma_f32_32x32x16_bf16(fa0, fb1, a01, 0, 0, 0);
      a10 = __builtin_amdgcn_mfma_f32_32x32x16_bf16(fa1, fb0, a10, 0, 0, 0);
      a11 = __builtin_amdgcn_mfma_f32_32x32x16_bf16(fa1, fb1, a11, 0, 0, 0);
    }
  }
#undef STG_TILE
#undef FRA
#undef FRB

  // inline stats (reuses As as f64 scratch; barrier inside protects K-loop reads)
  float mS, rS;
  stats_reduce(partIn, npIn, (double*)&As[0][0], mS, rS, 512);

  const bool q3 = (N == 3072);
  float ls = 0.f, lsq = 0.f;
  const long rowT = rA0 + wm*64 + 4*hi;
  const long colT = rB0 + wn*64 + lr;
#pragma unroll
  for (int nt = 0; nt < 2; ++nt) {
    const long col = colT + nt*32;
    float bv;
    if (MODE == 3 && q3)
      bv = col < 1024 ? ba[col] : col < 2048 ? bb[col - 1024] : bc[col - 2048];
    else
      bv = ba[col];
    float beta = 0.f;
    if (MODE == 3 || MODE == 4) beta = bv - mS*rS*cs[col];
#pragma unroll
    for (int mt = 0; mt < 2; ++mt) {
      const f32x16 acc = mt == 0 ? (nt == 0 ? a00 : a01) : (nt == 0 ? a10 : a11);
#pragma unroll
      for (int r = 0; r < 16; ++r) {
        const long row = rowT + mt*32 + (r & 3) + 8*(r >> 2);
        const long off = row*(long)N + col;
        float v;
        if (MODE == 3)      v = fmaf(acc[r], rS, beta);
        else if (MODE == 4) v = fmaxf(fmaf(acc[r], rS, beta), 0.f);
        else {
          v = acc[r] + bv + ((float)res[off] - mS)*rS;
          ls += v; lsq += v*v;
        }
        outB[off] = (bf16_t)v;
      }
    }
  }
  if (MODE == 5) {
    rs[tid] = ls; rq[tid] = lsq;
    __syncthreads();
    for (int o = 256; o > 0; o >>= 1) {
      if (tid < o) { rs[tid] += rs[tid+o]; rq[tid] += rq[tid+o]; }
      __syncthreads();
    }
    if (tid == 0) { part[2*blockIdx.x] = rs[0]; part[2*blockIdx.x + 1] = rq[0]; }
  }
}

// ========== MFMA attention: one block per (b, head), 4 waves ===============
// Phase 1 (double-buffered): S = Q.K^T; raw s_barrier + counted vmcnt(8).
// Softmax in-register; P normalized to bf16 LDS. Phase 2: O = P.V with V
// transposed into LDS and next-chunk V register prefetch.
__global__ __launch_bounds__(256) void attn_m(
    const bf16_t* __restrict__ qkv, bf16_t* __restrict__ ob)
{
  __shared__ __align__(16) bf16_t Qb[2][8192];   // 32 KB
  __shared__ __align__(16) bf16_t Kb[2][8192];   // 32 KB
  __shared__ __align__(16) bf16_t Ps[4096];      // 8 KB
  bf16_t* Vs = &Qb[0][0];                        // [128][64] (phase 2)
  bf16_t* Os = &Kb[0][0];                        // [64][128] (phase 2)

  const int tid = threadIdx.x;
  const int w = tid >> 6, l = tid & 63;
  const int fr = l & 15, kq = l >> 4;
  const int head = blockIdx.x & 7, b = blockIdx.x >> 3;
  const long rbase = (long)head*32 + b;

  const int lr  = tid >> 2;                      // staging row 0..63
  const int sslot = (tid & 15) ^ (tid >> 4);     // pre-swizzled Q/K src slot

  f32x4 accS[4] = {{0,0,0,0},{0,0,0,0},{0,0,0,0},{0,0,0,0}};

#define STAGE_QK(qb, kb, kc) do { \
    _Pragma("unroll") for (int i_ = 0; i_ < 4; ++i_) { \
      const int r_ = i_*16 + (tid >> 4); \
      const long gq_ = ((long)r_*256 + rbase)*QKVS + (kc) + sslot*8; \
      gload_lds16(qkv + gq_,        (char*)(qb) + i_*4096 + w*1024); \
      gload_lds16(qkv + gq_ + 1024, (char*)(kb) + i_*4096 + w*1024); \
    } } while (0)

  // ---------------- phase 1: S = Q.K^T over K=1024, double-buffered --------
  STAGE_QK(Qb[0], Kb[0], 0);
#pragma unroll
  for (int c = 0; c < 8; ++c) {
    const int cur = c & 1;
    if (c < 7) {
      STAGE_QK(Qb[cur ^ 1], Kb[cur ^ 1], (c + 1)*128);
      asm volatile("s_waitcnt vmcnt(8)" ::: "memory");
    } else {
      asm volatile("s_waitcnt vmcnt(0)" ::: "memory");
    }
    BAR();                                       // chunk c resident
#pragma unroll
    for (int kk = 0; kk < 4; ++kk) {
      const int ra = w*16 + fr;
      bf16x8 a = *(const bf16x8*)&Qb[cur][ra*128 + (((kk*4 + kq) ^ fr) << 3)];
#pragma unroll
      for (int n = 0; n < 4; ++n) {
        const int rb = n*16 + fr;
        bf16x8 bv = *(const bf16x8*)&Kb[cur][rb*128 + (((kk*4 + kq) ^ fr) << 3)];
        accS[n] = __builtin_amdgcn_mfma_f32_16x16x32_bf16(a, bv, accS[n], 0, 0, 0);
      }
    }
    BAR();                                       // all reads done before restage
  }
#undef STAGE_QK

  // ---------------- softmax (rows live in 16-lane groups) ------------------
  const float scale = 0.08838834764831843f;      // 1/sqrt(128)
  float pj[4][4];
#pragma unroll
  for (int j = 0; j < 4; ++j) {
    float m = fmaxf(fmaxf(accS[0][j], accS[1][j]), fmaxf(accS[2][j], accS[3][j]));
    m = fmaxf(m, __shfl_xor(m, 1));
    m = fmaxf(m, __shfl_xor(m, 2));
    m = fmaxf(m, __shfl_xor(m, 4));
    m = fmaxf(m, __shfl_xor(m, 8));
    m *= scale;
    float s = 0.f;
#pragma unroll
    for (int n = 0; n < 4; ++n) { pj[n][j] = __expf(accS[n][j]*scale - m); s += pj[n][j]; }
    s += __shfl_xor(s, 1);
    s += __shfl_xor(s, 2);
    s += __shfl_xor(s, 4);
    s += __shfl_xor(s, 8);
    const float rv = 1.f / s;
#pragma unroll
    for (int n = 0; n < 4; ++n) pj[n][j] *= rv;
  }
#pragma unroll
  for (int n = 0; n < 4; ++n)
#pragma unroll
    for (int j = 0; j < 4; ++j) {
      const int r = w*16 + kq*4 + j;
      const int cpos = n*16 + fr;
      Ps[r*64 + (((cpos >> 3) ^ (r & 7)) << 3) + (cpos & 7)] = (bf16_t)pj[n][j];
    }
  __syncthreads();                               // P visible; Qb/Kb free

  // ---------------- phase 2: O = P.V, 128-feature chunks, V prefetch -------
  const long orow = (long)lr*256 + b*8 + head;
  const bf16_t* vbase = qkv + ((long)lr*256 + rbase)*QKVS + 2048;
  const int ra2 = w*16 + fr;
  bf16x8 a0 = *(const bf16x8*)&Ps[ra2*64 + ((kq       ^ (ra2 & 7)) << 3)];
  bf16x8 a1 = *(const bf16x8*)&Ps[ra2*64 + (((4 + kq) ^ (ra2 & 7)) << 3)];

  uint4 vr[4];
#pragma unroll
  for (int i = 0; i < 4; ++i)
    vr[i] = *(const uint4*)&vbase[(tid & 3)*8 + i*32];

#pragma unroll
  for (int fc8 = 0; fc8 < 8; ++fc8) {
    // transpose-write current V chunk into Vs[f][s] (slot-swizzled)
#pragma unroll
    for (int i = 0; i < 4; ++i) {
      const int f0 = (tid & 3)*8 + i*32;
      const bf16_t* ve = (const bf16_t*)&vr[i];
#pragma unroll
      for (int j = 0; j < 8; ++j) {
        const int f = f0 + j;
        Vs[f*64 + (((lr >> 3) ^ (f & 7)) << 3) + (lr & 7)] = ve[j];
      }
    }
    __syncthreads();
    // prefetch next chunk's V into registers (hides under MFMA+Os)
    if (fc8 < 7) {
#pragma unroll
      for (int i = 0; i < 4; ++i)
        vr[i] = *(const uint4*)&vbase[(fc8 + 1)*128 + (tid & 3)*8 + i*32];
    }
    f32x4 accO[8];
#pragma unroll
    for (int nt = 0; nt < 8; ++nt) {
      const int f = nt*16 + fr;
      bf16x8 b0 = *(const bf16x8*)&Vs[f*64 + ((kq       ^ (f & 7)) << 3)];
      bf16x8 b1 = *(const bf16x8*)&Vs[f*64 + (((4 + kq) ^ (f & 7)) << 3)];
      accO[nt] = __builtin_amdgcn_mfma_f32_16x16x32_bf16(a0, b0, (f32x4){0.f,0.f,0.f,0.f}, 0, 0, 0);
      accO[nt] = __builtin_amdgcn_mfma_f32_16x16x32_bf16(a1, b1, accO[nt], 0, 0, 0);
    }
#pragma unroll
    for (int nt = 0; nt < 8; ++nt)
#pragma unroll
      for (int j = 0; j < 4; ++j) {
        const int r = w*16 + kq*4 + j;
        const int cpos = nt*16 + fr;
        Os[r*128 + (((cpos >> 3) ^ (r & 7)) << 3) + (cpos & 7)] = (bf16_t)accO[nt][j];
      }
    __syncthreads();
#pragma unroll
    for (int i = 0; i < 4; ++i) {
      const int p = (tid & 3)*4 + i;             // logical 16B slot 0..15
      uint4 vv = *(const uint4*)&Os[lr*128 + ((p ^ (lr & 7)) << 3)];
      *(uint4*)&ob[orow*HID + fc8*128 + p*8] = vv;
    }
  }
}

// -------- final: d_out(f32) = (t2_raw - mean)*rstd (inline stats) ----------
__global__ __launch_bounds__(256) void final_norm(const bf16_t* __restrict__ t,
    const float* __restrict__ part, int np, float* __restrict__ out)
{
  __shared__ double shd[16];
  float m, r;
  stats_reduce(part, np, shd, m, r, 256);
  const long n8 = NTOT / 8;
  for (long i = (long)blockIdx.x*blockDim.x + threadIdx.x; i < n8;
       i += (long)gridDim.x*blockDim.x) {
    bf16x8 v = ((const bf16x8*)t)[i];
    float4 o0 = {((float)v[0]-m)*r, ((float)v[1]-m)*r, ((float)v[2]-m)*r, ((float)v[3]-m)*r};
    float4 o1 = {((float)v[4]-m)*r, ((float)v[5]-m)*r, ((float)v[6]-m)*r, ((float)v[7]-m)*r};
    ((float4*)out)[2*i]   = o0;
    ((float4*)out)[2*i+1] = o1;
  }
}

// ---------------------------------------------------------------------------
extern "C" void kernel_launch(void* const* d_in, const int* in_sizes, int n_in,
                              void* d_out, int out_size, void* d_ws, size_t ws_size,
                              hipStream_t stream)
{
  const int*   x    = (const int*)  d_in[0];
  const float* emb  = (const float*)d_in[1];
  const float* pos  = (const float*)d_in[2];
  const float* wq_a = (const float*)d_in[3];
  const float* bq_a = (const float*)d_in[4];
  const float* wk_a = (const float*)d_in[5];
  const float* bk_a = (const float*)d_in[6];
  const float* wv_a = (const float*)d_in[7];
  const float* bv_a = (const float*)d_in[8];
  const float* wo_a = (const float*)d_in[9];
  const float* bo_a = (const float*)d_in[10];
  const float* w1_a = (const float*)d_in[11];
  const float* b1_a = (const float*)d_in[12];
  const float* w2_a = (const float*)d_in[13];
  const float* b2_a = (const float*)d_in[14];

  char* p = (char*)d_ws;
  auto take = [&](size_t n) { char* r = p; p += (n + 255) & ~(size_t)255; return r; };
  bf16_t* hb   = (bf16_t*)take(NTOT*2);                 // raw hidden (rolling)
  bf16_t* U    = (bf16_t*)take((size_t)NROW*FFD*2);     // 128 MB union
  bf16_t* qkv  = U;                                     // NROW x 3072
  bf16_t* attb = U + 3*NTOT;
  bf16_t* ffb  = U;                                     // overlays qkv (dead)
  bf16_t* wTo  = (bf16_t*)take((size_t)HID*HID*2);
  bf16_t* wT1  = (bf16_t*)take((size_t)HID*FFD*2);
  bf16_t* wT2  = (bf16_t*)take((size_t)HID*FFD*2);
  bf16_t* wT3  = (bf16_t*)take((size_t)3*HID*HID*2);
  float*  cs1  = (float*) take(FFD*4);
  float*  cs3  = (float*) take(QKVS*4);
  float*  part1= (float*) take(2048*4);
  float*  part2= (float*) take(2048*4);

  const int gQKV = (NROW/128)*(QKVS/256);   // 1536
  const int gH   = (NROW/128)*(HID/256);    // 512
  const int gF   = (NROW/128)*(FFD/256);    // 2048

  embed_k<<<NROW, 256, 0, stream>>>(x, emb, pos, hb);
  prep0<<<102, 512, 0, stream>>>(wq_a, wk_a, wv_a, wT3, cs3);

  for (int i = 0; i < 6; ++i) {
    const float* Bq = bq_a + (size_t)i*HID;
    const float* Bk = bk_a + (size_t)i*HID;
    const float* Bv = bv_a + (size_t)i*HID;
    const float* Wo = wo_a + (size_t)i*HID*HID;  const float* Bo = bo_a + (size_t)i*HID;
    const float* W1 = w1_a + (size_t)i*HID*FFD;  const float* B1 = b1_a + (size_t)i*FFD;
    const float* W2 = w2_a + (size_t)i*FFD*HID;  const float* B2 = b2_a + (size_t)i*HID;
    const int npIn = (i == 0) ? 0 : gH;          // identity at layer 0
    const int haveNext = (i < 5);
    const float* Wqn = wq_a + (size_t)(i+1)*HID*HID;
    const float* Wkn = wk_a + (size_t)(i+1)*HID*HID;
    const float* Wvn = wv_a + (size_t)(i+1)*HID*HID;

    // QKV projection (LN-fold; stats inlined from part2)
    gemmW<3><<<gQKV, 512, 0, stream>>>(hb, wT3, Bq, Bk, Bv, cs3, part2, npIn,
                                       nullptr, qkv, nullptr, NROW, QKVS, HID);

    attn_m<<<256, 256, 0, stream>>>(qkv, attb);

    // standalone LDS-free weight prep for this layer (+ next-layer QKV)
    prep_k<<<haveNext ? 398 : 296, 512, 0, stream>>>(
        Wo, wTo, W1, wT1, cs1, W2, wT2, Wqn, Wkn, Wvn, wT3, cs3);

    // wo projection + residual fold + LN partials -> part1
    gemmW<5><<<gH, 512, 0, stream>>>(attb, wTo, Bo, Bo, Bo, nullptr, part2, npIn,
                                     hb, hb, part1, NROW, HID, HID);

    // FFN1 (LN-fold + relu; stats from part1)
    gemmW<4><<<gF, 512, 0, stream>>>(hb, wT1, B1, B1, B1, cs1, part1, gH,
                                     nullptr, ffb, nullptr, NROW, FFD, HID);

    // FFN2 + residual fold + LN partials -> part2
    gemmW<5><<<gH, 512, 0, stream>>>(ffb, wT2, B2, B2, B2, nullptr, part1, gH,
                                     hb, hb, part2, NROW, HID, FFD);
  }

  final_norm<<<2048, 256, 0, stream>>>(hb, part2, gH, (float*)d_out);
}